// Round 1
// baseline (370.552 us; speedup 1.0000x reference)
//
#include <hip/hip_runtime.h>

#define NB 2
#define SQ 512
#define SKV 4096
#define HID 1024
#define NH 16
#define NHK 4
#define NG 4
#define HD 64
#define EPSF 1e-6f

typedef short v8s __attribute__((ext_vector_type(8)));
typedef short v4s __attribute__((ext_vector_type(4)));
typedef float v4f __attribute__((ext_vector_type(4)));

static __device__ __forceinline__ short f2bf(float f) {
  unsigned u = __builtin_bit_cast(unsigned, f);
  u += 0x7FFFu + ((u >> 16) & 1u);
  return (short)(u >> 16);
}

// swizzled LDS fragment read: row-major [R][64] bf16 tile, 128B rows,
// byte ^= (row&7)<<4  (conflict-free for 16-row x 4-group b128 reads)
static __device__ __forceinline__ v8s lds_frag(const short* lds, int row, int kbyte) {
  return *(const v8s*)((const char*)lds + row * 128 + (kbyte ^ ((row & 7) << 4)));
}

// stage a 64x64 tile (rows r0.., cols c0..) into swizzled LDS; converts f32->bf16 if SRC_F32
template<int SRC_F32>
static __device__ __forceinline__ void stage_tile(const void* src, int ld,
                                                  int r0, int c0, short* lds, int t) {
#pragma unroll
  for (int i = 0; i < 2; ++i) {
    int flat = t * 8 + i * 2048;
    int row = flat >> 6, col = flat & 63;
    v8s v;
    if (SRC_F32) {
      const float* p = (const float*)src + (size_t)(r0 + row) * ld + c0 + col;
      v4f a = *(const v4f*)p;
      v4f b = *(const v4f*)(p + 4);
      v[0] = f2bf(a[0]); v[1] = f2bf(a[1]); v[2] = f2bf(a[2]); v[3] = f2bf(a[3]);
      v[4] = f2bf(b[0]); v[5] = f2bf(b[1]); v[6] = f2bf(b[2]); v[7] = f2bf(b[3]);
    } else {
      v = *(const v8s*)((const short*)src + (size_t)(r0 + row) * ld + c0 + col);
    }
    *(v8s*)((char*)lds + row * 128 + ((col * 2) ^ ((row & 7) << 4))) = v;
  }
}

// C[M,N] = A[M,K] * B[N,K]^T ; A f32-or-bf16, B f32; C f32. 64x64x64 tiles, 4 waves.
template<int A_F32>
__global__ __launch_bounds__(256) void gemm_bt(const void* __restrict__ Ap,
                                               const float* __restrict__ Bp,
                                               float* __restrict__ C,
                                               int M, int N, int K) {
  __shared__ __align__(16) short Asm[64 * 64];
  __shared__ __align__(16) short Bsm[64 * 64];
  const int t = threadIdx.x;
  const int lane = t & 63, w = t >> 6;
  const int l15 = lane & 15, g4 = lane >> 4;
  const int m0 = blockIdx.x * 64, n0 = blockIdx.y * 64;
  const int wr = (w >> 1) * 32, wc = (w & 1) * 32;
  v4f acc[2][2] = {};
  for (int k0 = 0; k0 < K; k0 += 64) {
    __syncthreads();
    stage_tile<A_F32>(Ap, K, m0, k0, Asm, t);
    stage_tile<1>(Bp, K, n0, k0, Bsm, t);
    __syncthreads();
    v8s af[2][2], bfr[2][2];
#pragma unroll
    for (int mf = 0; mf < 2; ++mf)
#pragma unroll
      for (int s = 0; s < 2; ++s)
        af[mf][s] = lds_frag(Asm, wr + mf * 16 + l15, s * 64 + g4 * 16);
#pragma unroll
    for (int nf = 0; nf < 2; ++nf)
#pragma unroll
      for (int s = 0; s < 2; ++s)
        bfr[nf][s] = lds_frag(Bsm, wc + nf * 16 + l15, s * 64 + g4 * 16);
#pragma unroll
    for (int mf = 0; mf < 2; ++mf)
#pragma unroll
      for (int nf = 0; nf < 2; ++nf)
#pragma unroll
        for (int s = 0; s < 2; ++s)
          acc[mf][nf] = __builtin_amdgcn_mfma_f32_16x16x32_bf16(af[mf][s], bfr[nf][s],
                                                                acc[mf][nf], 0, 0, 0);
  }
#pragma unroll
  for (int mf = 0; mf < 2; ++mf)
#pragma unroll
    for (int nf = 0; nf < 2; ++nf)
#pragma unroll
      for (int r = 0; r < 4; ++r) {
        int row = wr + mf * 16 + g4 * 4 + r;
        int col = wc + nf * 16 + l15;
        C[(size_t)(m0 + row) * N + n0 + col] = acc[mf][nf][r];
      }
}

// RMSNorm over D=64 per (b, s, h) row-unit + relayout to [b, nh, S, 64] bf16
__global__ __launch_bounds__(256) void rmsnorm_relayout(const float* __restrict__ X,
                                                        const float* __restrict__ wn,
                                                        short* __restrict__ out,
                                                        int S, int nh) {
  int w = threadIdx.x >> 6, lane = threadIdx.x & 63;
  int u = blockIdx.x * 4 + w;
  int b = u / (S * nh);
  int rem = u - b * S * nh;
  int s = rem / nh;
  int h = rem - s * nh;
  float x = X[(size_t)u * 64 + lane];
  float ss = x * x;
#pragma unroll
  for (int m = 1; m < 64; m <<= 1) ss += __shfl_xor(ss, m);
  float sc = rsqrtf(ss * (1.0f / 64.0f) + EPSF) * wn[lane];
  out[(((size_t)b * nh + h) * S + s) * 64 + lane] = f2bf(x * sc);
}

// v_f32 [B*SKV, NHK*64] -> Vt bf16 [B,NHK,64,SKV]
__global__ __launch_bounds__(256) void transpose_v(const float* __restrict__ V32,
                                                   short* __restrict__ Vt) {
  __shared__ float tile[64][65];
  int id = blockIdx.x;
  int kvt = id & 63, hk = (id >> 6) & 3, b = id >> 8;
  int t = threadIdx.x;
#pragma unroll
  for (int i = 0; i < 4; ++i) {
    int flat = i * 1024 + t * 4;
    int r = flat >> 6, c = flat & 63;
    v4f v = *(const v4f*)(V32 + ((size_t)(b * SKV + kvt * 64 + r)) * (NHK * HD) + hk * 64 + c);
    tile[r][c] = v[0]; tile[r][c + 1] = v[1]; tile[r][c + 2] = v[2]; tile[r][c + 3] = v[3];
  }
  __syncthreads();
#pragma unroll
  for (int i = 0; i < 4; ++i) {
    int flat = i * 1024 + t * 4;
    int d = flat >> 6, kv = flat & 63;
    v4s o;
#pragma unroll
    for (int j = 0; j < 4; ++j) o[j] = f2bf(tile[kv + j][d]);
    *(v4s*)(Vt + ((size_t)(b * NHK + hk) * 64 + d) * SKV + kvt * 64 + kv) = o;
  }
}

// Flash attention: block = (b, hk, qt16); 4 waves = 4 GQA heads sharing K/V tiles.
// Q bf16 [B,NH,SQ,64]; K bf16 [B,NHK,SKV,64]; Vt bf16 [B,NHK,64,SKV]; out bf16 [B,SQ,1024]
__global__ __launch_bounds__(256) void attn_kernel(const short* __restrict__ Qb,
                                                   const short* __restrict__ Kb,
                                                   const short* __restrict__ Vt,
                                                   short* __restrict__ Ob) {
  __shared__ __align__(16) short Ksm[64 * 64];
  __shared__ __align__(16) short Vsm[64 * 64];
  __shared__ __align__(16) short Psm[4][16 * 64];
  int id = blockIdx.x;
  int qt = id & 31, hk = (id >> 5) & 3, b = id >> 7;
  int t = threadIdx.x, w = t >> 6, lane = t & 63;
  int l15 = lane & 15, g4 = lane >> 4;
  int h = hk * NG + w;

  const short* qbase = Qb + (((size_t)(b * NH + h)) * SQ + qt * 16) * 64;
  v8s aq[2];
#pragma unroll
  for (int s = 0; s < 2; ++s)
    aq[s] = *(const v8s*)(qbase + (size_t)l15 * 64 + s * 32 + g4 * 8);

  const short* kbase = Kb + ((size_t)(b * NHK + hk)) * SKV * 64;
  const short* vbase = Vt + ((size_t)(b * NHK + hk)) * 64 * SKV;
  char* pbase = (char*)&Psm[w][0];

  v4f acco[4] = {};
  float mrow[4], lrow[4];
#pragma unroll
  for (int r = 0; r < 4; ++r) { mrow[r] = -__builtin_inff(); lrow[r] = 0.f; }

  for (int kt = 0; kt < SKV / 64; ++kt) {
    __syncthreads();
    stage_tile<0>(kbase, 64, kt * 64, 0, Ksm, t);    // K tile: [kv][d]
    stage_tile<0>(vbase, SKV, 0, kt * 64, Vsm, t);   // Vt tile: [d][kv]
    __syncthreads();

    // S = Q K^T  (per wave: 16 q-rows x 64 kv)
    v4f accs[4] = {};
#pragma unroll
    for (int f = 0; f < 4; ++f)
#pragma unroll
      for (int s = 0; s < 2; ++s) {
        v8s bk = lds_frag(Ksm, f * 16 + l15, s * 64 + g4 * 16);
        accs[f] = __builtin_amdgcn_mfma_f32_16x16x32_bf16(aq[s], bk, accs[f], 0, 0, 0);
      }

    // online softmax (f32); value at (q = g4*4+r, kv = f*16 + l15)
    float tm[4];
#pragma unroll
    for (int r = 0; r < 4; ++r)
      tm[r] = fmaxf(fmaxf(accs[0][r], accs[1][r]), fmaxf(accs[2][r], accs[3][r]));
#pragma unroll
    for (int msk = 1; msk < 16; msk <<= 1)
#pragma unroll
      for (int r = 0; r < 4; ++r)
        tm[r] = fmaxf(tm[r], __shfl_xor(tm[r], msk));
    float al[4];
#pragma unroll
    for (int r = 0; r < 4; ++r) {
      float mn = fmaxf(mrow[r], tm[r]);
      al[r] = __expf(mrow[r] - mn);
      mrow[r] = mn;
    }
    float pv[4][4], rs[4] = {0.f, 0.f, 0.f, 0.f};
#pragma unroll
    for (int f = 0; f < 4; ++f)
#pragma unroll
      for (int r = 0; r < 4; ++r) {
        pv[f][r] = __expf(accs[f][r] - mrow[r]);
        rs[r] += pv[f][r];
      }
#pragma unroll
    for (int msk = 1; msk < 16; msk <<= 1)
#pragma unroll
      for (int r = 0; r < 4; ++r) rs[r] += __shfl_xor(rs[r], msk);
#pragma unroll
    for (int r = 0; r < 4; ++r) lrow[r] = lrow[r] * al[r] + rs[r];
#pragma unroll
    for (int fd = 0; fd < 4; ++fd)
#pragma unroll
      for (int r = 0; r < 4; ++r) acco[fd][r] *= al[r];

    // P -> per-wave LDS (bf16, swizzled), then read back as A-fragments
#pragma unroll
    for (int f = 0; f < 4; ++f)
#pragma unroll
      for (int r = 0; r < 4; ++r) {
        int row = g4 * 4 + r;
        int colB = (f * 16 + l15) * 2;
        *(short*)(pbase + row * 128 + (colB ^ ((row & 7) << 4))) = f2bf(pv[f][r]);
      }
    asm volatile("s_waitcnt lgkmcnt(0)" ::: "memory");
    __builtin_amdgcn_sched_barrier(0);
    v8s pa[2];
#pragma unroll
    for (int s = 0; s < 2; ++s)
      pa[s] = *(const v8s*)(pbase + l15 * 128 + ((s * 64 + g4 * 16) ^ ((l15 & 7) << 4)));
#pragma unroll
    for (int fd = 0; fd < 4; ++fd)
#pragma unroll
      for (int s = 0; s < 2; ++s) {
        v8s vb = lds_frag(Vsm, fd * 16 + l15, s * 64 + g4 * 16);
        acco[fd] = __builtin_amdgcn_mfma_f32_16x16x32_bf16(pa[s], vb, acco[fd], 0, 0, 0);
      }
  }

  // epilogue: out[b, sq, h*64 + d] = acco / l
#pragma unroll
  for (int fd = 0; fd < 4; ++fd)
#pragma unroll
    for (int r = 0; r < 4; ++r) {
      int row = g4 * 4 + r;
      int sq = qt * 16 + row;
      float o = acco[fd][r] / lrow[r];
      Ob[((size_t)(b * SQ + sq)) * HID + h * HD + fd * 16 + l15] = f2bf(o);
    }
}

extern "C" void kernel_launch(void* const* d_in, const int* in_sizes, int n_in,
                              void* d_out, int out_size, void* d_ws, size_t ws_size,
                              hipStream_t stream) {
  const float* inputs = (const float*)d_in[0];  // [B,SKV,1024]
  const float* latent = (const float*)d_in[1];  // [B,SQ,1024]
  const float* wq = (const float*)d_in[2];      // [1024,1024]
  const float* wk = (const float*)d_in[3];      // [256,1024]
  const float* wv = (const float*)d_in[4];      // [256,1024]
  const float* wo = (const float*)d_in[5];      // [1024,1024]
  const float* qnw = (const float*)d_in[6];     // [64]
  const float* knw = (const float*)d_in[7];     // [64]

  char* ws = (char*)d_ws;
  float* q_f32 = (float*)(ws);                  //  4 MB [1024,1024]
  float* k_f32 = (float*)(ws + 4194304);        //  8 MB [8192,256]
  float* v_f32 = (float*)(ws + 12582912);       //  8 MB [8192,256]
  short* Qb    = (short*)(ws + 20971520);       //  2 MB [B,NH,SQ,64]
  short* Kb    = (short*)(ws + 23068672);       //  4 MB [B,NHK,SKV,64]
  short* Vtb   = (short*)(ws + 27262976);       //  4 MB [B,NHK,64,SKV]
  short* Ab    = (short*)(ws + 31457280);       //  2 MB [B,SQ,1024]

  gemm_bt<1><<<dim3(16, 16), 256, 0, stream>>>(latent, wq, q_f32, 1024, 1024, 1024);
  gemm_bt<1><<<dim3(128, 4), 256, 0, stream>>>(inputs, wk, k_f32, 8192, 256, 1024);
  gemm_bt<1><<<dim3(128, 4), 256, 0, stream>>>(inputs, wv, v_f32, 8192, 256, 1024);
  rmsnorm_relayout<<<4096, 256, 0, stream>>>(q_f32, qnw, Qb, SQ, NH);
  rmsnorm_relayout<<<8192, 256, 0, stream>>>(k_f32, knw, Kb, SKV, NHK);
  transpose_v<<<512, 256, 0, stream>>>(v_f32, Vtb);
  attn_kernel<<<256, 256, 0, stream>>>(Qb, Kb, Vtb, Ab);
  gemm_bt<0><<<dim3(16, 16), 256, 0, stream>>>(Ab, wo, (float*)d_out, 1024, 1024, 1024);
}

// Round 4
// 268.139 us; speedup vs baseline: 1.3819x; 1.3819x over previous
//
#include <hip/hip_runtime.h>

#define NB 2
#define SQ 512
#define SKV 4096
#define HID 1024
#define NH 16
#define NHK 4
#define NG 4
#define HD 64
#define EPSF 1e-6f
#define NSPLIT 4
#define RB (NB * NH * SQ)  // 16384 total q-rows

typedef short v8s __attribute__((ext_vector_type(8)));
typedef short v4s __attribute__((ext_vector_type(4)));
typedef float v4f __attribute__((ext_vector_type(4)));
typedef float v2f __attribute__((ext_vector_type(2)));

static __device__ __forceinline__ short f2bf(float f) {
  unsigned u = __builtin_bit_cast(unsigned, f);
  u += 0x7FFFu + ((u >> 16) & 1u);
  return (short)(u >> 16);
}

// swizzled LDS fragment read: row-major [R][64] bf16 tile, 128B rows,
// byte ^= (row&7)<<4  (conflict-free for 16-row x 4-group b128 reads)
static __device__ __forceinline__ v8s lds_frag(const short* lds, int row, int kbyte) {
  return *(const v8s*)((const char*)lds + row * 128 + (kbyte ^ ((row & 7) << 4)));
}

// stage a 64x64 tile (rows r0.., cols c0..) into swizzled LDS; converts f32->bf16 if SRC_F32
template<int SRC_F32>
static __device__ __forceinline__ void stage_tile(const void* src, int ld,
                                                  int r0, int c0, short* lds, int t) {
#pragma unroll
  for (int i = 0; i < 2; ++i) {
    int flat = t * 8 + i * 2048;
    int row = flat >> 6, col = flat & 63;
    v8s v;
    if (SRC_F32) {
      const float* p = (const float*)src + (size_t)(r0 + row) * ld + c0 + col;
      v4f a = *(const v4f*)p;
      v4f b = *(const v4f*)(p + 4);
      v[0] = f2bf(a[0]); v[1] = f2bf(a[1]); v[2] = f2bf(a[2]); v[3] = f2bf(a[3]);
      v[4] = f2bf(b[0]); v[5] = f2bf(b[1]); v[6] = f2bf(b[2]); v[7] = f2bf(b[3]);
    } else {
      v = *(const v8s*)((const short*)src + (size_t)(r0 + row) * ld + c0 + col);
    }
    *(v8s*)((char*)lds + row * 128 + ((col * 2) ^ ((row & 7) << 4))) = v;
  }
}

// C[M,N] = A[M,K] * B[N,K]^T ; A f32-or-bf16, B f32; C f32. 64x64x64 tiles, 4 waves.
template<int A_F32>
__global__ __launch_bounds__(256) void gemm_bt(const void* __restrict__ Ap,
                                               const float* __restrict__ Bp,
                                               float* __restrict__ C,
                                               int M, int N, int K) {
  __shared__ __align__(16) short Asm[64 * 64];
  __shared__ __align__(16) short Bsm[64 * 64];
  const int t = threadIdx.x;
  const int lane = t & 63, w = t >> 6;
  const int l15 = lane & 15, g4 = lane >> 4;
  const int m0 = blockIdx.x * 64, n0 = blockIdx.y * 64;
  const int wr = (w >> 1) * 32, wc = (w & 1) * 32;
  v4f acc[2][2] = {};
  for (int k0 = 0; k0 < K; k0 += 64) {
    __syncthreads();
    stage_tile<A_F32>(Ap, K, m0, k0, Asm, t);
    stage_tile<1>(Bp, K, n0, k0, Bsm, t);
    __syncthreads();
    v8s af[2][2], bfr[2][2];
#pragma unroll
    for (int mf = 0; mf < 2; ++mf)
#pragma unroll
      for (int s = 0; s < 2; ++s)
        af[mf][s] = lds_frag(Asm, wr + mf * 16 + l15, s * 64 + g4 * 16);
#pragma unroll
    for (int nf = 0; nf < 2; ++nf)
#pragma unroll
      for (int s = 0; s < 2; ++s)
        bfr[nf][s] = lds_frag(Bsm, wc + nf * 16 + l15, s * 64 + g4 * 16);
#pragma unroll
    for (int mf = 0; mf < 2; ++mf)
#pragma unroll
      for (int nf = 0; nf < 2; ++nf)
#pragma unroll
        for (int s = 0; s < 2; ++s)
          acc[mf][nf] = __builtin_amdgcn_mfma_f32_16x16x32_bf16(af[mf][s], bfr[nf][s],
                                                                acc[mf][nf], 0, 0, 0);
  }
#pragma unroll
  for (int mf = 0; mf < 2; ++mf)
#pragma unroll
    for (int nf = 0; nf < 2; ++nf)
#pragma unroll
      for (int r = 0; r < 4; ++r) {
        int row = wr + mf * 16 + g4 * 4 + r;
        int col = wc + nf * 16 + l15;
        C[(size_t)(m0 + row) * N + n0 + col] = acc[mf][nf][r];
      }
}

// RMSNorm over D=64 per (b, s, h) row-unit + relayout to [b, nh, S, 64] bf16
__global__ __launch_bounds__(256) void rmsnorm_relayout(const float* __restrict__ X,
                                                        const float* __restrict__ wn,
                                                        short* __restrict__ out,
                                                        int S, int nh) {
  int w = threadIdx.x >> 6, lane = threadIdx.x & 63;
  int u = blockIdx.x * 4 + w;
  int b = u / (S * nh);
  int rem = u - b * S * nh;
  int s = rem / nh;
  int h = rem - s * nh;
  float x = X[(size_t)u * 64 + lane];
  float ss = x * x;
#pragma unroll
  for (int m = 1; m < 64; m <<= 1) ss += __shfl_xor(ss, m);
  float sc = rsqrtf(ss * (1.0f / 64.0f) + EPSF) * wn[lane];
  out[(((size_t)b * nh + h) * S + s) * 64 + lane] = f2bf(x * sc);
}

// v_f32 [B*SKV, NHK*64] -> Vt bf16 [B,NHK,64,SKV]
__global__ __launch_bounds__(256) void transpose_v(const float* __restrict__ V32,
                                                   short* __restrict__ Vt) {
  __shared__ float tile[64][65];
  int id = blockIdx.x;
  int kvt = id & 63, hk = (id >> 6) & 3, b = id >> 8;
  int t = threadIdx.x;
#pragma unroll
  for (int i = 0; i < 4; ++i) {
    int flat = i * 1024 + t * 4;
    int r = flat >> 6, c = flat & 63;
    v4f v = *(const v4f*)(V32 + ((size_t)(b * SKV + kvt * 64 + r)) * (NHK * HD) + hk * 64 + c);
    tile[r][c] = v[0]; tile[r][c + 1] = v[1]; tile[r][c + 2] = v[2]; tile[r][c + 3] = v[3];
  }
  __syncthreads();
#pragma unroll
  for (int i = 0; i < 4; ++i) {
    int flat = i * 1024 + t * 4;
    int d = flat >> 6, kv = flat & 63;
    v4s o;
#pragma unroll
    for (int j = 0; j < 4; ++j) o[j] = f2bf(tile[kv + j][d]);
    *(v4s*)(Vt + ((size_t)(b * NHK + hk) * 64 + d) * SKV + kvt * 64 + kv) = o;
  }
}

// Flash attention with KV-split: block = (split, b, hk, qt16); 4 waves = 4 GQA heads.
// Each block scans SKV/NSPLIT kv positions; emits unnormalized O partial + (m,l).
// Q bf16 [B,NH,SQ,64]; K bf16 [B,NHK,SKV,64]; Vt bf16 [B,NHK,64,SKV]
// Op f32 [NSPLIT, RB, 64]; Ml f32 [NSPLIT, RB, 2]
__global__ __launch_bounds__(256) void attn_kernel(const short* __restrict__ Qb,
                                                   const short* __restrict__ Kb,
                                                   const short* __restrict__ Vt,
                                                   float* __restrict__ Op,
                                                   float* __restrict__ Ml) {
  __shared__ __align__(16) short Ksm[64 * 64];
  __shared__ __align__(16) short Vsm[64 * 64];
  __shared__ __align__(16) short Psm[4][16 * 64];
  int id = blockIdx.x;
  int qt = id & 31, hk = (id >> 5) & 3, b = (id >> 7) & 1, sp = id >> 8;
  int t = threadIdx.x, w = t >> 6, lane = t & 63;
  int l15 = lane & 15, g4 = lane >> 4;
  int h = hk * NG + w;

  const short* qbase = Qb + (((size_t)(b * NH + h)) * SQ + qt * 16) * 64;
  v8s aq[2];
#pragma unroll
  for (int s = 0; s < 2; ++s)
    aq[s] = *(const v8s*)(qbase + (size_t)l15 * 64 + s * 32 + g4 * 8);

  const short* kbase = Kb + ((size_t)(b * NHK + hk)) * SKV * 64;
  const short* vbase = Vt + ((size_t)(b * NHK + hk)) * 64 * SKV;
  char* pbase = (char*)&Psm[w][0];

  v4f acco[4] = {};
  float mrow[4], lrow[4];
#pragma unroll
  for (int r = 0; r < 4; ++r) { mrow[r] = -__builtin_inff(); lrow[r] = 0.f; }

  const int KT0 = sp * (SKV / NSPLIT / 64);
  for (int kt2 = 0; kt2 < SKV / NSPLIT / 64; ++kt2) {
    int kt = KT0 + kt2;
    __syncthreads();
    stage_tile<0>(kbase, 64, kt * 64, 0, Ksm, t);    // K tile: [kv][d]
    stage_tile<0>(vbase, SKV, 0, kt * 64, Vsm, t);   // Vt tile: [d][kv]
    __syncthreads();

    // S = Q K^T  (per wave: 16 q-rows x 64 kv)
    v4f accs[4] = {};
#pragma unroll
    for (int f = 0; f < 4; ++f)
#pragma unroll
      for (int s = 0; s < 2; ++s) {
        v8s bk = lds_frag(Ksm, f * 16 + l15, s * 64 + g4 * 16);
        accs[f] = __builtin_amdgcn_mfma_f32_16x16x32_bf16(aq[s], bk, accs[f], 0, 0, 0);
      }

    // online softmax (f32); value at (q = g4*4+r, kv = f*16 + l15)
    float tm[4];
#pragma unroll
    for (int r = 0; r < 4; ++r)
      tm[r] = fmaxf(fmaxf(accs[0][r], accs[1][r]), fmaxf(accs[2][r], accs[3][r]));
#pragma unroll
    for (int msk = 1; msk < 16; msk <<= 1)
#pragma unroll
      for (int r = 0; r < 4; ++r)
        tm[r] = fmaxf(tm[r], __shfl_xor(tm[r], msk));
    float al[4];
#pragma unroll
    for (int r = 0; r < 4; ++r) {
      float mn = fmaxf(mrow[r], tm[r]);
      al[r] = __expf(mrow[r] - mn);
      mrow[r] = mn;
    }
    float pv[4][4], rs[4] = {0.f, 0.f, 0.f, 0.f};
#pragma unroll
    for (int f = 0; f < 4; ++f)
#pragma unroll
      for (int r = 0; r < 4; ++r) {
        pv[f][r] = __expf(accs[f][r] - mrow[r]);
        rs[r] += pv[f][r];
      }
#pragma unroll
    for (int msk = 1; msk < 16; msk <<= 1)
#pragma unroll
      for (int r = 0; r < 4; ++r) rs[r] += __shfl_xor(rs[r], msk);
#pragma unroll
    for (int r = 0; r < 4; ++r) lrow[r] = lrow[r] * al[r] + rs[r];
#pragma unroll
    for (int fd = 0; fd < 4; ++fd)
#pragma unroll
      for (int r = 0; r < 4; ++r) acco[fd][r] *= al[r];

    // P -> per-wave LDS (bf16, swizzled), then read back as A-fragments
#pragma unroll
    for (int f = 0; f < 4; ++f)
#pragma unroll
      for (int r = 0; r < 4; ++r) {
        int row = g4 * 4 + r;
        int colB = (f * 16 + l15) * 2;
        *(short*)(pbase + row * 128 + (colB ^ ((row & 7) << 4))) = f2bf(pv[f][r]);
      }
    asm volatile("s_waitcnt lgkmcnt(0)" ::: "memory");
    __builtin_amdgcn_sched_barrier(0);
    v8s pa[2];
#pragma unroll
    for (int s = 0; s < 2; ++s)
      pa[s] = *(const v8s*)(pbase + l15 * 128 + ((s * 64 + g4 * 16) ^ ((l15 & 7) << 4)));
#pragma unroll
    for (int fd = 0; fd < 4; ++fd)
#pragma unroll
      for (int s = 0; s < 2; ++s) {
        v8s vb = lds_frag(Vsm, fd * 16 + l15, s * 64 + g4 * 16);
        acco[fd] = __builtin_amdgcn_mfma_f32_16x16x32_bf16(pa[s], vb, acco[fd], 0, 0, 0);
      }
  }

  // epilogue: write unnormalized partial O + (m,l) per row
  size_t rowbase = ((size_t)b * NH + h) * SQ + qt * 16;
#pragma unroll
  for (int fd = 0; fd < 4; ++fd)
#pragma unroll
    for (int r = 0; r < 4; ++r) {
      int row = g4 * 4 + r;
      Op[((size_t)sp * RB + rowbase + row) * 64 + fd * 16 + l15] = acco[fd][r];
    }
  if (l15 == 0) {
#pragma unroll
    for (int r = 0; r < 4; ++r) {
      int row = g4 * 4 + r;
      v2f ml; ml[0] = mrow[r]; ml[1] = lrow[r];
      *(v2f*)(Ml + ((size_t)sp * RB + rowbase + row) * 2) = ml;
    }
  }
}

// Merge NSPLIT partials -> Ab bf16 [B, SQ, H*64]
__global__ __launch_bounds__(256) void merge_attn(const float* __restrict__ Op,
                                                  const float* __restrict__ Ml,
                                                  short* __restrict__ Ab) {
  int idx = blockIdx.x * 256 + threadIdx.x;  // RB*64 total
  int d = idx & 63, row = idx >> 6;
  float ms[NSPLIT], ls[NSPLIT];
  float M = -__builtin_inff();
#pragma unroll
  for (int s = 0; s < NSPLIT; ++s) {
    v2f ml = *(const v2f*)(Ml + ((size_t)s * RB + row) * 2);
    ms[s] = ml[0]; ls[s] = ml[1];
    M = fmaxf(M, ms[s]);
  }
  float L = 0.f, o = 0.f;
#pragma unroll
  for (int s = 0; s < NSPLIT; ++s) {
    float wgt = __expf(ms[s] - M);
    L += ls[s] * wgt;
    o += wgt * Op[((size_t)s * RB + row) * 64 + d];
  }
  int b = row >> 13;
  int hh = (row >> 9) & 15;
  int sq = row & 511;
  Ab[((size_t)(b * SQ + sq)) * HID + hh * 64 + d] = f2bf(o / L);
}

extern "C" void kernel_launch(void* const* d_in, const int* in_sizes, int n_in,
                              void* d_out, int out_size, void* d_ws, size_t ws_size,
                              hipStream_t stream) {
  const float* inputs = (const float*)d_in[0];  // [B,SKV,1024]
  const float* latent = (const float*)d_in[1];  // [B,SQ,1024]
  const float* wq = (const float*)d_in[2];      // [1024,1024]
  const float* wk = (const float*)d_in[3];      // [256,1024]
  const float* wv = (const float*)d_in[4];      // [256,1024]
  const float* wo = (const float*)d_in[5];      // [1024,1024]
  const float* qnw = (const float*)d_in[6];     // [64]
  const float* knw = (const float*)d_in[7];     // [64]

  char* ws = (char*)d_ws;
  float* q_f32 = (float*)(ws);                  //  4 MB [1024,1024]
  float* k_f32 = (float*)(ws + 4194304);        //  8 MB [8192,256]
  float* v_f32 = (float*)(ws + 12582912);       //  8 MB [8192,256]
  short* Qb    = (short*)(ws + 20971520);       //  2 MB [B,NH,SQ,64]
  short* Kb    = (short*)(ws + 23068672);       //  4 MB [B,NHK,SKV,64]
  short* Vtb   = (short*)(ws + 27262976);       //  4 MB [B,NHK,64,SKV]
  short* Ab    = (short*)(ws + 31457280);       //  2 MB [B,SQ,1024]
  // attention partials REUSE the q/k/v f32 staging region (dead after preproc):
  float* Op    = (float*)(ws);                  // 16 MB [NSPLIT, RB, 64]
  float* Ml    = (float*)(ws + 16777216);       // 0.5 MB [NSPLIT, RB, 2]

  gemm_bt<1><<<dim3(16, 16), 256, 0, stream>>>(latent, wq, q_f32, 1024, 1024, 1024);
  gemm_bt<1><<<dim3(128, 4), 256, 0, stream>>>(inputs, wk, k_f32, 8192, 256, 1024);
  gemm_bt<1><<<dim3(128, 4), 256, 0, stream>>>(inputs, wv, v_f32, 8192, 256, 1024);
  rmsnorm_relayout<<<4096, 256, 0, stream>>>(q_f32, qnw, Qb, SQ, NH);
  rmsnorm_relayout<<<8192, 256, 0, stream>>>(k_f32, knw, Kb, SKV, NHK);
  transpose_v<<<512, 256, 0, stream>>>(v_f32, Vtb);
  attn_kernel<<<256 * NSPLIT, 256, 0, stream>>>(Qb, Kb, Vtb, Op, Ml);
  merge_attn<<<RB * 64 / 256, 256, 0, stream>>>(Op, Ml, Ab);
  gemm_bt<0><<<dim3(16, 16), 256, 0, stream>>>(Ab, wo, (float*)d_out, 1024, 1024, 1024);
}

// Round 7
// 247.348 us; speedup vs baseline: 1.4981x; 1.0841x over previous
//
#include <hip/hip_runtime.h>

#define NB 2
#define SQ 512
#define SKV 4096
#define HID 1024
#define NH 16
#define NHK 4
#define NG 4
#define HD 64
#define EPSF 1e-6f
#define NSPLIT 4
#define RB (NB * NH * SQ)  // 16384 total q-rows

typedef short v8s __attribute__((ext_vector_type(8)));
typedef short v4s __attribute__((ext_vector_type(4)));
typedef float v4f __attribute__((ext_vector_type(4)));
typedef float v2f __attribute__((ext_vector_type(2)));

static __device__ __forceinline__ short f2bf(float f) {
  unsigned u = __builtin_bit_cast(unsigned, f);
  u += 0x7FFFu + ((u >> 16) & 1u);
  return (short)(u >> 16);
}

// swizzled LDS fragment read: row-major [R][64] bf16 tile, 128B rows,
// byte ^= (row&7)<<4  (conflict-free for 16-row x 4-group b128 reads)
static __device__ __forceinline__ v8s lds_frag(const short* lds, int row, int kbyte) {
  return *(const v8s*)((const char*)lds + row * 128 + (kbyte ^ ((row & 7) << 4)));
}

// stage a 64x64 tile (rows r0.., cols c0..) into swizzled LDS; converts f32->bf16 if SRC_F32
template<int SRC_F32>
static __device__ __forceinline__ void stage_tile(const void* src, int ld,
                                                  int r0, int c0, short* lds, int t) {
#pragma unroll
  for (int i = 0; i < 2; ++i) {
    int flat = t * 8 + i * 2048;
    int row = flat >> 6, col = flat & 63;
    v8s v;
    if (SRC_F32) {
      const float* p = (const float*)src + (size_t)(r0 + row) * ld + c0 + col;
      v4f a = *(const v4f*)p;
      v4f b = *(const v4f*)(p + 4);
      v[0] = f2bf(a[0]); v[1] = f2bf(a[1]); v[2] = f2bf(a[2]); v[3] = f2bf(a[3]);
      v[4] = f2bf(b[0]); v[5] = f2bf(b[1]); v[6] = f2bf(b[2]); v[7] = f2bf(b[3]);
    } else {
      v = *(const v8s*)((const short*)src + (size_t)(r0 + row) * ld + c0 + col);
    }
    *(v8s*)((char*)lds + row * 128 + ((col * 2) ^ ((row & 7) << 4))) = v;
  }
}

// Fused projection: out = rmsnorm_or_raw(A @ W^T) in bf16, head-major layouts.
// KIND 0: Q  — A=latent  [NB*SQ,1024],  W=wq [NH*64,1024],  norm, out [B,NH,SQ,64]
// KIND 1: K  — A=inputs  [NB*SKV,1024], W=wk [NHK*64,1024], norm, out [B,NHK,SKV,64]
// KIND 2: V  — A=inputs,                W=wv,               no norm, out TRANSPOSED [B,NHK,64,SKV]
//   (V computes W-rows x A-rows so the accumulator is already [d][skv])
// Each of 4 waves owns 16 output rows x 64 cols -> per-row rmsnorm is a 16-lane reduce.
template<int KIND>
__global__ __launch_bounds__(256) void proj_kernel(const float* __restrict__ A,
                                                   const float* __restrict__ W,
                                                   const float* __restrict__ wn,
                                                   short* __restrict__ out) {
  const int S = (KIND == 0) ? SQ : SKV;
  const int LB = (KIND == 0) ? 9 : 12;
  const int nh = (KIND == 0) ? NH : NHK;
  __shared__ __align__(16) short Asm[64 * 64];
  __shared__ __align__(16) short Bsm[64 * 64];
  const int t = threadIdx.x, lane = t & 63, w = t >> 6;
  const int l15 = lane & 15, g4 = lane >> 4;
  const int m0 = blockIdx.x * 64;
  const int h = blockIdx.y;
  v4f acc[4] = {};
  for (int k0 = 0; k0 < HID; k0 += 64) {
    __syncthreads();
    stage_tile<1>(A, HID, m0, k0, Asm, t);
    stage_tile<1>(W, HID, h * 64, k0, Bsm, t);
    __syncthreads();
    const short* asrc = (KIND == 2) ? Bsm : Asm;  // first operand rows (output "row" dim)
    const short* bsrc = (KIND == 2) ? Asm : Bsm;  // second operand rows (output "col" dim)
    v8s af[2];
#pragma unroll
    for (int s = 0; s < 2; ++s)
      af[s] = lds_frag(asrc, w * 16 + l15, s * 64 + g4 * 16);
#pragma unroll
    for (int nf = 0; nf < 4; ++nf)
#pragma unroll
      for (int s = 0; s < 2; ++s) {
        v8s bf = lds_frag(bsrc, nf * 16 + l15, s * 64 + g4 * 16);
        acc[nf] = __builtin_amdgcn_mfma_f32_16x16x32_bf16(af[s], bf, acc[nf], 0, 0, 0);
      }
  }
  if (KIND != 2) {
    float wcol[4];
#pragma unroll
    for (int nf = 0; nf < 4; ++nf) wcol[nf] = wn[nf * 16 + l15];
#pragma unroll
    for (int r = 0; r < 4; ++r) {
      float ss = acc[0][r] * acc[0][r] + acc[1][r] * acc[1][r] +
                 acc[2][r] * acc[2][r] + acc[3][r] * acc[3][r];
#pragma unroll
      for (int msk = 1; msk < 16; msk <<= 1) ss += __shfl_xor(ss, msk);
      float sc = rsqrtf(ss * (1.0f / 64.0f) + EPSF);
      int m = m0 + w * 16 + g4 * 4 + r;
      int b = m >> LB, sl = m & (S - 1);
      size_t base = ((size_t)(b * nh + h) * S + sl) * 64;
#pragma unroll
      for (int nf = 0; nf < 4; ++nf)
        out[base + nf * 16 + l15] = f2bf(acc[nf][r] * sc * wcol[nf]);
    }
  } else {
#pragma unroll
    for (int r = 0; r < 4; ++r) {
      int d = w * 16 + g4 * 4 + r;
#pragma unroll
      for (int nf = 0; nf < 4; ++nf) {
        int skv = m0 + nf * 16 + l15;
        int b = skv >> 12, sl = skv & (SKV - 1);
        out[((size_t)(b * NHK + h) * 64 + d) * SKV + sl] = f2bf(acc[nf][r]);
      }
    }
  }
}

// C[M,N] = A[M,K](bf16) * B[N,K]^T(f32) ; C f32. 64x64x64 tiles, 4 waves. (wo projection)
__global__ __launch_bounds__(256) void gemm_bt(const short* __restrict__ Ap,
                                               const float* __restrict__ Bp,
                                               float* __restrict__ C,
                                               int M, int N, int K) {
  __shared__ __align__(16) short Asm[64 * 64];
  __shared__ __align__(16) short Bsm[64 * 64];
  const int t = threadIdx.x;
  const int lane = t & 63, w = t >> 6;
  const int l15 = lane & 15, g4 = lane >> 4;
  const int m0 = blockIdx.x * 64, n0 = blockIdx.y * 64;
  const int wr = (w >> 1) * 32, wc = (w & 1) * 32;
  v4f acc[2][2] = {};
  for (int k0 = 0; k0 < K; k0 += 64) {
    __syncthreads();
    stage_tile<0>(Ap, K, m0, k0, Asm, t);
    stage_tile<1>(Bp, K, n0, k0, Bsm, t);
    __syncthreads();
    v8s af[2][2], bfr[2][2];
#pragma unroll
    for (int mf = 0; mf < 2; ++mf)
#pragma unroll
      for (int s = 0; s < 2; ++s)
        af[mf][s] = lds_frag(Asm, wr + mf * 16 + l15, s * 64 + g4 * 16);
#pragma unroll
    for (int nf = 0; nf < 2; ++nf)
#pragma unroll
      for (int s = 0; s < 2; ++s)
        bfr[nf][s] = lds_frag(Bsm, wc + nf * 16 + l15, s * 64 + g4 * 16);
#pragma unroll
    for (int mf = 0; mf < 2; ++mf)
#pragma unroll
      for (int nf = 0; nf < 2; ++nf)
#pragma unroll
        for (int s = 0; s < 2; ++s)
          acc[mf][nf] = __builtin_amdgcn_mfma_f32_16x16x32_bf16(af[mf][s], bfr[nf][s],
                                                                acc[mf][nf], 0, 0, 0);
  }
#pragma unroll
  for (int mf = 0; mf < 2; ++mf)
#pragma unroll
    for (int nf = 0; nf < 2; ++nf)
#pragma unroll
      for (int r = 0; r < 4; ++r) {
        int row = wr + mf * 16 + g4 * 4 + r;
        int col = wc + nf * 16 + l15;
        C[(size_t)(m0 + row) * N + n0 + col] = acc[mf][nf][r];
      }
}

// Flash attention, KV-split, KVBLK=128 (two 64-tiles per barrier pair, batched softmax).
// block = (split, b, hk, qt16); 4 waves = 4 GQA heads sharing K/V tiles.
// Q bf16 [B,NH,SQ,64]; K bf16 [B,NHK,SKV,64]; Vt bf16 [B,NHK,64,SKV]
// Op f32 [NSPLIT, RB, 64]; Ml f32 [NSPLIT, RB, 2]
__global__ __launch_bounds__(256) void attn_kernel(const short* __restrict__ Qb,
                                                   const short* __restrict__ Kb,
                                                   const short* __restrict__ Vt,
                                                   float* __restrict__ Op,
                                                   float* __restrict__ Ml) {
  __shared__ __align__(16) short Ksm[2][64 * 64];
  __shared__ __align__(16) short Vsm[2][64 * 64];
  __shared__ __align__(16) short Psm[4][16 * 64];
  int id = blockIdx.x;
  int qt = id & 31, hk = (id >> 5) & 3, b = (id >> 7) & 1, sp = id >> 8;
  int t = threadIdx.x, w = t >> 6, lane = t & 63;
  int l15 = lane & 15, g4 = lane >> 4;
  int h = hk * NG + w;

  const short* qbase = Qb + (((size_t)(b * NH + h)) * SQ + qt * 16) * 64;
  v8s aq[2];
#pragma unroll
  for (int s = 0; s < 2; ++s)
    aq[s] = *(const v8s*)(qbase + (size_t)l15 * 64 + s * 32 + g4 * 8);

  const short* kbase = Kb + ((size_t)(b * NHK + hk)) * SKV * 64;
  const short* vbase = Vt + ((size_t)(b * NHK + hk)) * 64 * SKV;
  char* pbase = (char*)&Psm[w][0];

  v4f acco[4] = {};
  float mrow[4], lrow[4];
#pragma unroll
  for (int r = 0; r < 4; ++r) { mrow[r] = -__builtin_inff(); lrow[r] = 0.f; }

  const int KV0 = sp * (SKV / NSPLIT);
  for (int kt = 0; kt < SKV / NSPLIT / 128; ++kt) {
    int kv0 = KV0 + kt * 128;
    __syncthreads();
    stage_tile<0>(kbase, 64, kv0, 0, Ksm[0], t);       // K rows kv0..+64
    stage_tile<0>(kbase, 64, kv0 + 64, 0, Ksm[1], t);  // K rows +64..+128
    stage_tile<0>(vbase, SKV, 0, kv0, Vsm[0], t);      // Vt cols kv0..+64
    stage_tile<0>(vbase, SKV, 0, kv0 + 64, Vsm[1], t);
    __syncthreads();

    // S = Q K^T over 128 kv (8 fragments)
    v4f accs[8] = {};
#pragma unroll
    for (int hf = 0; hf < 2; ++hf)
#pragma unroll
      for (int f = 0; f < 4; ++f)
#pragma unroll
        for (int s = 0; s < 2; ++s) {
          v8s bk = lds_frag(Ksm[hf], f * 16 + l15, s * 64 + g4 * 16);
          accs[hf * 4 + f] =
              __builtin_amdgcn_mfma_f32_16x16x32_bf16(aq[s], bk, accs[hf * 4 + f], 0, 0, 0);
        }

    // batched online softmax over 128 kv; element (q = g4*4+r, kv = (f&3)*16+l15 + (f>>2)*64)
    float tm[4];
#pragma unroll
    for (int r = 0; r < 4; ++r) {
      float m01 = fmaxf(accs[0][r], accs[1][r]), m23 = fmaxf(accs[2][r], accs[3][r]);
      float m45 = fmaxf(accs[4][r], accs[5][r]), m67 = fmaxf(accs[6][r], accs[7][r]);
      tm[r] = fmaxf(fmaxf(m01, m23), fmaxf(m45, m67));
    }
#pragma unroll
    for (int msk = 1; msk < 16; msk <<= 1)
#pragma unroll
      for (int r = 0; r < 4; ++r)
        tm[r] = fmaxf(tm[r], __shfl_xor(tm[r], msk));
    float al[4];
#pragma unroll
    for (int r = 0; r < 4; ++r) {
      float mn = fmaxf(mrow[r], tm[r]);
      al[r] = __expf(mrow[r] - mn);
      mrow[r] = mn;
    }
    float rs[4] = {0.f, 0.f, 0.f, 0.f};
#pragma unroll
    for (int f = 0; f < 8; ++f)
#pragma unroll
      for (int r = 0; r < 4; ++r) {
        accs[f][r] = __expf(accs[f][r] - mrow[r]);  // exp in-place (P values)
        rs[r] += accs[f][r];
      }
#pragma unroll
    for (int msk = 1; msk < 16; msk <<= 1)
#pragma unroll
      for (int r = 0; r < 4; ++r) rs[r] += __shfl_xor(rs[r], msk);
#pragma unroll
    for (int r = 0; r < 4; ++r) lrow[r] = lrow[r] * al[r] + rs[r];
#pragma unroll
    for (int fd = 0; fd < 4; ++fd)
#pragma unroll
      for (int r = 0; r < 4; ++r) acco[fd][r] *= al[r];

    // PV in two 64-kv halves through per-wave LDS (Psm reused per half)
#pragma unroll
    for (int hf = 0; hf < 2; ++hf) {
#pragma unroll
      for (int f = 0; f < 4; ++f)
#pragma unroll
        for (int r = 0; r < 4; ++r) {
          int row = g4 * 4 + r;
          int colB = (f * 16 + l15) * 2;
          *(short*)(pbase + row * 128 + (colB ^ ((row & 7) << 4))) = f2bf(accs[hf * 4 + f][r]);
        }
      asm volatile("s_waitcnt lgkmcnt(0)" ::: "memory");
      __builtin_amdgcn_sched_barrier(0);
      v8s pa[2];
#pragma unroll
      for (int s = 0; s < 2; ++s)
        pa[s] = *(const v8s*)(pbase + l15 * 128 + ((s * 64 + g4 * 16) ^ ((l15 & 7) << 4)));
      asm volatile("s_waitcnt lgkmcnt(0)" ::: "memory");
      __builtin_amdgcn_sched_barrier(0);
#pragma unroll
      for (int fd = 0; fd < 4; ++fd)
#pragma unroll
        for (int s = 0; s < 2; ++s) {
          v8s vb = lds_frag(Vsm[hf], fd * 16 + l15, s * 64 + g4 * 16);
          acco[fd] = __builtin_amdgcn_mfma_f32_16x16x32_bf16(pa[s], vb, acco[fd], 0, 0, 0);
        }
    }
  }

  // epilogue: write unnormalized partial O + (m,l) per row
  size_t rowbase = ((size_t)b * NH + h) * SQ + qt * 16;
#pragma unroll
  for (int fd = 0; fd < 4; ++fd)
#pragma unroll
    for (int r = 0; r < 4; ++r) {
      int row = g4 * 4 + r;
      Op[((size_t)sp * RB + rowbase + row) * 64 + fd * 16 + l15] = acco[fd][r];
    }
  if (l15 == 0) {
#pragma unroll
    for (int r = 0; r < 4; ++r) {
      int row = g4 * 4 + r;
      v2f ml; ml[0] = mrow[r]; ml[1] = lrow[r];
      *(v2f*)(Ml + ((size_t)sp * RB + rowbase + row) * 2) = ml;
    }
  }
}

// Merge NSPLIT partials -> Ab bf16 [B, SQ, H*64]
__global__ __launch_bounds__(256) void merge_attn(const float* __restrict__ Op,
                                                  const float* __restrict__ Ml,
                                                  short* __restrict__ Ab) {
  int idx = blockIdx.x * 256 + threadIdx.x;  // RB*64 total
  int d = idx & 63, row = idx >> 6;
  float ms[NSPLIT], ls[NSPLIT];
  float M = -__builtin_inff();
#pragma unroll
  for (int s = 0; s < NSPLIT; ++s) {
    v2f ml = *(const v2f*)(Ml + ((size_t)s * RB + row) * 2);
    ms[s] = ml[0]; ls[s] = ml[1];
    M = fmaxf(M, ms[s]);
  }
  float L = 0.f, o = 0.f;
#pragma unroll
  for (int s = 0; s < NSPLIT; ++s) {
    float wgt = __expf(ms[s] - M);
    L += ls[s] * wgt;
    o += wgt * Op[((size_t)s * RB + row) * 64 + d];
  }
  int b = row >> 13;
  int hh = (row >> 9) & 15;
  int sq = row & 511;
  Ab[((size_t)(b * SQ + sq)) * HID + hh * 64 + d] = f2bf(o / L);
}

extern "C" void kernel_launch(void* const* d_in, const int* in_sizes, int n_in,
                              void* d_out, int out_size, void* d_ws, size_t ws_size,
                              hipStream_t stream) {
  const float* inputs = (const float*)d_in[0];  // [B,SKV,1024]
  const float* latent = (const float*)d_in[1];  // [B,SQ,1024]
  const float* wq = (const float*)d_in[2];      // [1024,1024]
  const float* wk = (const float*)d_in[3];      // [256,1024]
  const float* wv = (const float*)d_in[4];      // [256,1024]
  const float* wo = (const float*)d_in[5];      // [1024,1024]
  const float* qnw = (const float*)d_in[6];     // [64]
  const float* knw = (const float*)d_in[7];     // [64]

  char* ws = (char*)d_ws;
  float* Op  = (float*)(ws);                    // 16 MB  [NSPLIT, RB, 64]
  float* Ml  = (float*)(ws + 16777216);         // 0.5 MB [NSPLIT, RB, 2]
  short* Qb  = (short*)(ws + 17825792);         // 2 MB   [B,NH,SQ,64]
  short* Kb  = (short*)(ws + 19922944);         // 4 MB   [B,NHK,SKV,64]
  short* Vtb = (short*)(ws + 24117248);         // 4 MB   [B,NHK,64,SKV]
  short* Ab  = (short*)(ws + 28311552);         // 2 MB   [B,SQ,1024]

  proj_kernel<0><<<dim3(16, 16), 256, 0, stream>>>(latent, wq, qnw, Qb);
  proj_kernel<1><<<dim3(128, 4), 256, 0, stream>>>(inputs, wk, knw, Kb);
  proj_kernel<2><<<dim3(128, 4), 256, 0, stream>>>(inputs, wv, knw, Vtb);
  attn_kernel<<<256 * NSPLIT, 256, 0, stream>>>(Qb, Kb, Vtb, Op, Ml);
  merge_attn<<<RB * 64 / 256, 256, 0, stream>>>(Op, Ml, Ab);
  gemm_bt<<<dim3(16, 16), 256, 0, stream>>>(Ab, wo, (float*)d_out, 1024, 1024, 1024);
}

// Round 8
// 240.826 us; speedup vs baseline: 1.5387x; 1.0271x over previous
//
#include <hip/hip_runtime.h>

#define NB 2
#define SQ 512
#define SKV 4096
#define HID 1024
#define NH 16
#define NHK 4
#define NG 4
#define HD 64
#define EPSF 1e-6f
#define NSPLIT 4
#define RB (NB * NH * SQ)  // 16384 total q-rows

typedef short v8s __attribute__((ext_vector_type(8)));
typedef short v4s __attribute__((ext_vector_type(4)));
typedef float v4f __attribute__((ext_vector_type(4)));
typedef float v2f __attribute__((ext_vector_type(2)));

static __device__ __forceinline__ short f2bf(float f) {
  unsigned u = __builtin_bit_cast(unsigned, f);
  u += 0x7FFFu + ((u >> 16) & 1u);
  return (short)(u >> 16);
}

// swizzled LDS fragment read: row-major [R][64] bf16 tile, 128B rows,
// byte ^= (row&7)<<4  (conflict-free for 16-row x 4-group b128 reads)
static __device__ __forceinline__ v8s lds_frag(const short* lds, int row, int kbyte) {
  return *(const v8s*)((const char*)lds + row * 128 + (kbyte ^ ((row & 7) << 4)));
}

// stage a (NIT*32)x64 tile (rows r0.., cols c0..) into swizzled LDS; f32->bf16 if SRC_F32
template<int SRC_F32, int NIT>
static __device__ __forceinline__ void stage_tile(const void* src, int ld,
                                                  int r0, int c0, short* lds, int t) {
#pragma unroll
  for (int i = 0; i < NIT; ++i) {
    int flat = t * 8 + i * 2048;
    int row = flat >> 6, col = flat & 63;
    v8s v;
    if (SRC_F32) {
      const float* p = (const float*)src + (size_t)(r0 + row) * ld + c0 + col;
      v4f a = *(const v4f*)p;
      v4f b = *(const v4f*)(p + 4);
      v[0] = f2bf(a[0]); v[1] = f2bf(a[1]); v[2] = f2bf(a[2]); v[3] = f2bf(a[3]);
      v[4] = f2bf(b[0]); v[5] = f2bf(b[1]); v[6] = f2bf(b[2]); v[7] = f2bf(b[3]);
    } else {
      v = *(const v8s*)((const short*)src + (size_t)(r0 + row) * ld + c0 + col);
    }
    *(v8s*)((char*)lds + row * 128 + ((col * 2) ^ ((row & 7) << 4))) = v;
  }
}

// Fused K+V projection. grid (M/128, 2, 2): x=m-block, y=head-pair, z={0:K,1:V}.
// BM=128, BN=128 (2 heads), 4 waves 2x2, wave owns 64x64 (16 acc frags).
// K: rmsnorm epilogue -> Kb [B,NHK,SKV,64]. V: transposed write -> Vtb [B,NHK,64,SKV].
__global__ __launch_bounds__(256) void proj_kv(const float* __restrict__ A,
                                               const float* __restrict__ Wk,
                                               const float* __restrict__ Wv,
                                               const float* __restrict__ knw,
                                               short* __restrict__ Kb,
                                               short* __restrict__ Vtb) {
  __shared__ __align__(16) short Asm[128 * 64];
  __shared__ __align__(16) short Bsm[128 * 64];
  const int t = threadIdx.x, lane = t & 63, w = t >> 6;
  const int l15 = lane & 15, g4 = lane >> 4;
  const int wr = w >> 1, wc = w & 1;
  const int m0 = blockIdx.x * 128, n0 = blockIdx.y * 128;
  const int isV = blockIdx.z;
  const float* W = isV ? Wv : Wk;
  v4f acc[4][4] = {};
  for (int k0 = 0; k0 < HID; k0 += 64) {
    __syncthreads();
    stage_tile<1, 4>(A, HID, m0, k0, Asm, t);
    stage_tile<1, 4>(W, HID, n0, k0, Bsm, t);
    __syncthreads();
    v8s af[4][2], bfr[4][2];
#pragma unroll
    for (int mf = 0; mf < 4; ++mf)
#pragma unroll
      for (int s = 0; s < 2; ++s)
        af[mf][s] = lds_frag(Asm, wr * 64 + mf * 16 + l15, s * 64 + g4 * 16);
#pragma unroll
    for (int nf = 0; nf < 4; ++nf)
#pragma unroll
      for (int s = 0; s < 2; ++s)
        bfr[nf][s] = lds_frag(Bsm, wc * 64 + nf * 16 + l15, s * 64 + g4 * 16);
#pragma unroll
    for (int mf = 0; mf < 4; ++mf)
#pragma unroll
      for (int nf = 0; nf < 4; ++nf)
#pragma unroll
        for (int s = 0; s < 2; ++s)
          acc[mf][nf] = __builtin_amdgcn_mfma_f32_16x16x32_bf16(af[mf][s], bfr[nf][s],
                                                                acc[mf][nf], 0, 0, 0);
  }
  const int head = blockIdx.y * 2 + wc;
  if (!isV) {
    float wcol[4];
#pragma unroll
    for (int nf = 0; nf < 4; ++nf) wcol[nf] = knw[nf * 16 + l15];
#pragma unroll
    for (int mf = 0; mf < 4; ++mf)
#pragma unroll
      for (int j = 0; j < 4; ++j) {
        float ss = acc[mf][0][j] * acc[mf][0][j] + acc[mf][1][j] * acc[mf][1][j] +
                   acc[mf][2][j] * acc[mf][2][j] + acc[mf][3][j] * acc[mf][3][j];
#pragma unroll
        for (int msk = 1; msk < 16; msk <<= 1) ss += __shfl_xor(ss, msk);
        float sc = rsqrtf(ss * (1.0f / 64.0f) + EPSF);
        int m = m0 + wr * 64 + mf * 16 + g4 * 4 + j;
        int b = m >> 12, sl = m & (SKV - 1);
        size_t base = ((size_t)(b * NHK + head) * SKV + sl) * 64;
#pragma unroll
        for (int nf = 0; nf < 4; ++nf)
          Kb[base + nf * 16 + l15] = f2bf(acc[mf][nf][j] * sc * wcol[nf]);
      }
  } else {
#pragma unroll
    for (int mf = 0; mf < 4; ++mf) {
      int m = m0 + wr * 64 + mf * 16 + g4 * 4;
      int b = m >> 12, sl = m & (SKV - 1);
#pragma unroll
      for (int nf = 0; nf < 4; ++nf) {
        int d = nf * 16 + l15;
        v4s o;
#pragma unroll
        for (int j = 0; j < 4; ++j) o[j] = f2bf(acc[mf][nf][j]);
        *(v4s*)(Vtb + ((size_t)(b * NHK + head) * 64 + d) * SKV + sl) = o;
      }
    }
  }
}

// Q projection (KIND 0: A f32 latent, rmsnorm -> Qb bf16) and WO gemm (KIND 1: A bf16 Ab,
// plain f32 C -> d_out). BM=64, BN=128, 4 waves 2x2, wave owns 32x64 (8 acc frags).
template<int KIND>
__global__ __launch_bounds__(256) void gemm64(const void* __restrict__ Ap,
                                              const float* __restrict__ W,
                                              const float* __restrict__ wn,
                                              void* __restrict__ outp) {
  __shared__ __align__(16) short Asm[64 * 64];
  __shared__ __align__(16) short Bsm[128 * 64];
  const int t = threadIdx.x, lane = t & 63, w = t >> 6;
  const int l15 = lane & 15, g4 = lane >> 4;
  const int wr = w >> 1, wc = w & 1;
  const int m0 = blockIdx.x * 64, n0 = blockIdx.y * 128;
  v4f acc[2][4] = {};
  for (int k0 = 0; k0 < HID; k0 += 64) {
    __syncthreads();
    stage_tile<(KIND == 0) ? 1 : 0, 2>(Ap, HID, m0, k0, Asm, t);
    stage_tile<1, 4>(W, HID, n0, k0, Bsm, t);
    __syncthreads();
    v8s af[2][2], bfr[4][2];
#pragma unroll
    for (int mf = 0; mf < 2; ++mf)
#pragma unroll
      for (int s = 0; s < 2; ++s)
        af[mf][s] = lds_frag(Asm, wr * 32 + mf * 16 + l15, s * 64 + g4 * 16);
#pragma unroll
    for (int nf = 0; nf < 4; ++nf)
#pragma unroll
      for (int s = 0; s < 2; ++s)
        bfr[nf][s] = lds_frag(Bsm, wc * 64 + nf * 16 + l15, s * 64 + g4 * 16);
#pragma unroll
    for (int mf = 0; mf < 2; ++mf)
#pragma unroll
      for (int nf = 0; nf < 4; ++nf)
#pragma unroll
        for (int s = 0; s < 2; ++s)
          acc[mf][nf] = __builtin_amdgcn_mfma_f32_16x16x32_bf16(af[mf][s], bfr[nf][s],
                                                                acc[mf][nf], 0, 0, 0);
  }
  if (KIND == 0) {
    short* outb = (short*)outp;
    const int head = blockIdx.y * 2 + wc;
    float wcol[4];
#pragma unroll
    for (int nf = 0; nf < 4; ++nf) wcol[nf] = wn[nf * 16 + l15];
#pragma unroll
    for (int mf = 0; mf < 2; ++mf)
#pragma unroll
      for (int j = 0; j < 4; ++j) {
        float ss = acc[mf][0][j] * acc[mf][0][j] + acc[mf][1][j] * acc[mf][1][j] +
                   acc[mf][2][j] * acc[mf][2][j] + acc[mf][3][j] * acc[mf][3][j];
#pragma unroll
        for (int msk = 1; msk < 16; msk <<= 1) ss += __shfl_xor(ss, msk);
        float sc = rsqrtf(ss * (1.0f / 64.0f) + EPSF);
        int m = m0 + wr * 32 + mf * 16 + g4 * 4 + j;
        int b = m >> 9, sl = m & (SQ - 1);
        size_t base = ((size_t)(b * NH + head) * SQ + sl) * 64;
#pragma unroll
        for (int nf = 0; nf < 4; ++nf)
          outb[base + nf * 16 + l15] = f2bf(acc[mf][nf][j] * sc * wcol[nf]);
      }
  } else {
    float* C = (float*)outp;
#pragma unroll
    for (int mf = 0; mf < 2; ++mf)
#pragma unroll
      for (int j = 0; j < 4; ++j) {
        int m = m0 + wr * 32 + mf * 16 + g4 * 4 + j;
#pragma unroll
        for (int nf = 0; nf < 4; ++nf)
          C[(size_t)m * HID + n0 + wc * 64 + nf * 16 + l15] = acc[mf][nf][j];
      }
  }
}

// Flash attention, KV-split, KVBLK=128 (two 64-tiles per barrier pair, batched softmax).
// block = (split, b, hk, qt16); 4 waves = 4 GQA heads sharing K/V tiles.  (UNCHANGED)
__global__ __launch_bounds__(256) void attn_kernel(const short* __restrict__ Qb,
                                                   const short* __restrict__ Kb,
                                                   const short* __restrict__ Vt,
                                                   float* __restrict__ Op,
                                                   float* __restrict__ Ml) {
  __shared__ __align__(16) short Ksm[2][64 * 64];
  __shared__ __align__(16) short Vsm[2][64 * 64];
  __shared__ __align__(16) short Psm[4][16 * 64];
  int id = blockIdx.x;
  int qt = id & 31, hk = (id >> 5) & 3, b = (id >> 7) & 1, sp = id >> 8;
  int t = threadIdx.x, w = t >> 6, lane = t & 63;
  int l15 = lane & 15, g4 = lane >> 4;
  int h = hk * NG + w;

  const short* qbase = Qb + (((size_t)(b * NH + h)) * SQ + qt * 16) * 64;
  v8s aq[2];
#pragma unroll
  for (int s = 0; s < 2; ++s)
    aq[s] = *(const v8s*)(qbase + (size_t)l15 * 64 + s * 32 + g4 * 8);

  const short* kbase = Kb + ((size_t)(b * NHK + hk)) * SKV * 64;
  const short* vbase = Vt + ((size_t)(b * NHK + hk)) * 64 * SKV;
  char* pbase = (char*)&Psm[w][0];

  v4f acco[4] = {};
  float mrow[4], lrow[4];
#pragma unroll
  for (int r = 0; r < 4; ++r) { mrow[r] = -__builtin_inff(); lrow[r] = 0.f; }

  const int KV0 = sp * (SKV / NSPLIT);
  for (int kt = 0; kt < SKV / NSPLIT / 128; ++kt) {
    int kv0 = KV0 + kt * 128;
    __syncthreads();
    stage_tile<0, 2>(kbase, 64, kv0, 0, Ksm[0], t);
    stage_tile<0, 2>(kbase, 64, kv0 + 64, 0, Ksm[1], t);
    stage_tile<0, 2>(vbase, SKV, 0, kv0, Vsm[0], t);
    stage_tile<0, 2>(vbase, SKV, 0, kv0 + 64, Vsm[1], t);
    __syncthreads();

    v4f accs[8] = {};
#pragma unroll
    for (int hf = 0; hf < 2; ++hf)
#pragma unroll
      for (int f = 0; f < 4; ++f)
#pragma unroll
        for (int s = 0; s < 2; ++s) {
          v8s bk = lds_frag(Ksm[hf], f * 16 + l15, s * 64 + g4 * 16);
          accs[hf * 4 + f] =
              __builtin_amdgcn_mfma_f32_16x16x32_bf16(aq[s], bk, accs[hf * 4 + f], 0, 0, 0);
        }

    float tm[4];
#pragma unroll
    for (int r = 0; r < 4; ++r) {
      float m01 = fmaxf(accs[0][r], accs[1][r]), m23 = fmaxf(accs[2][r], accs[3][r]);
      float m45 = fmaxf(accs[4][r], accs[5][r]), m67 = fmaxf(accs[6][r], accs[7][r]);
      tm[r] = fmaxf(fmaxf(m01, m23), fmaxf(m45, m67));
    }
#pragma unroll
    for (int msk = 1; msk < 16; msk <<= 1)
#pragma unroll
      for (int r = 0; r < 4; ++r)
        tm[r] = fmaxf(tm[r], __shfl_xor(tm[r], msk));
    float al[4];
#pragma unroll
    for (int r = 0; r < 4; ++r) {
      float mn = fmaxf(mrow[r], tm[r]);
      al[r] = __expf(mrow[r] - mn);
      mrow[r] = mn;
    }
    float rs[4] = {0.f, 0.f, 0.f, 0.f};
#pragma unroll
    for (int f = 0; f < 8; ++f)
#pragma unroll
      for (int r = 0; r < 4; ++r) {
        accs[f][r] = __expf(accs[f][r] - mrow[r]);
        rs[r] += accs[f][r];
      }
#pragma unroll
    for (int msk = 1; msk < 16; msk <<= 1)
#pragma unroll
      for (int r = 0; r < 4; ++r) rs[r] += __shfl_xor(rs[r], msk);
#pragma unroll
    for (int r = 0; r < 4; ++r) lrow[r] = lrow[r] * al[r] + rs[r];
#pragma unroll
    for (int fd = 0; fd < 4; ++fd)
#pragma unroll
      for (int r = 0; r < 4; ++r) acco[fd][r] *= al[r];

#pragma unroll
    for (int hf = 0; hf < 2; ++hf) {
#pragma unroll
      for (int f = 0; f < 4; ++f)
#pragma unroll
        for (int r = 0; r < 4; ++r) {
          int row = g4 * 4 + r;
          int colB = (f * 16 + l15) * 2;
          *(short*)(pbase + row * 128 + (colB ^ ((row & 7) << 4))) = f2bf(accs[hf * 4 + f][r]);
        }
      asm volatile("s_waitcnt lgkmcnt(0)" ::: "memory");
      __builtin_amdgcn_sched_barrier(0);
      v8s pa[2];
#pragma unroll
      for (int s = 0; s < 2; ++s)
        pa[s] = *(const v8s*)(pbase + l15 * 128 + ((s * 64 + g4 * 16) ^ ((l15 & 7) << 4)));
      asm volatile("s_waitcnt lgkmcnt(0)" ::: "memory");
      __builtin_amdgcn_sched_barrier(0);
#pragma unroll
      for (int fd = 0; fd < 4; ++fd)
#pragma unroll
        for (int s = 0; s < 2; ++s) {
          v8s vb = lds_frag(Vsm[hf], fd * 16 + l15, s * 64 + g4 * 16);
          acco[fd] = __builtin_amdgcn_mfma_f32_16x16x32_bf16(pa[s], vb, acco[fd], 0, 0, 0);
        }
    }
  }

  size_t rowbase = ((size_t)b * NH + h) * SQ + qt * 16;
#pragma unroll
  for (int fd = 0; fd < 4; ++fd)
#pragma unroll
    for (int r = 0; r < 4; ++r) {
      int row = g4 * 4 + r;
      Op[((size_t)sp * RB + rowbase + row) * 64 + fd * 16 + l15] = acco[fd][r];
    }
  if (l15 == 0) {
#pragma unroll
    for (int r = 0; r < 4; ++r) {
      int row = g4 * 4 + r;
      v2f ml; ml[0] = mrow[r]; ml[1] = lrow[r];
      *(v2f*)(Ml + ((size_t)sp * RB + rowbase + row) * 2) = ml;
    }
  }
}

// Merge NSPLIT partials -> Ab bf16 [B, SQ, H*64]
__global__ __launch_bounds__(256) void merge_attn(const float* __restrict__ Op,
                                                  const float* __restrict__ Ml,
                                                  short* __restrict__ Ab) {
  int idx = blockIdx.x * 256 + threadIdx.x;  // RB*64 total
  int d = idx & 63, row = idx >> 6;
  float ms[NSPLIT], ls[NSPLIT];
  float M = -__builtin_inff();
#pragma unroll
  for (int s = 0; s < NSPLIT; ++s) {
    v2f ml = *(const v2f*)(Ml + ((size_t)s * RB + row) * 2);
    ms[s] = ml[0]; ls[s] = ml[1];
    M = fmaxf(M, ms[s]);
  }
  float L = 0.f, o = 0.f;
#pragma unroll
  for (int s = 0; s < NSPLIT; ++s) {
    float wgt = __expf(ms[s] - M);
    L += ls[s] * wgt;
    o += wgt * Op[((size_t)s * RB + row) * 64 + d];
  }
  int b = row >> 13;
  int hh = (row >> 9) & 15;
  int sq = row & 511;
  Ab[((size_t)(b * SQ + sq)) * HID + hh * 64 + d] = f2bf(o / L);
}

extern "C" void kernel_launch(void* const* d_in, const int* in_sizes, int n_in,
                              void* d_out, int out_size, void* d_ws, size_t ws_size,
                              hipStream_t stream) {
  const float* inputs = (const float*)d_in[0];  // [B,SKV,1024]
  const float* latent = (const float*)d_in[1];  // [B,SQ,1024]
  const float* wq = (const float*)d_in[2];      // [1024,1024]
  const float* wk = (const float*)d_in[3];      // [256,1024]
  const float* wv = (const float*)d_in[4];      // [256,1024]
  const float* wo = (const float*)d_in[5];      // [1024,1024]
  const float* qnw = (const float*)d_in[6];     // [64]
  const float* knw = (const float*)d_in[7];     // [64]

  char* ws = (char*)d_ws;
  float* Op  = (float*)(ws);                    // 16 MB  [NSPLIT, RB, 64]
  float* Ml  = (float*)(ws + 16777216);         // 0.5 MB [NSPLIT, RB, 2]
  short* Qb  = (short*)(ws + 17825792);         // 2 MB   [B,NH,SQ,64]
  short* Kb  = (short*)(ws + 19922944);         // 4 MB   [B,NHK,SKV,64]
  short* Vtb = (short*)(ws + 24117248);         // 4 MB   [B,NHK,64,SKV]
  short* Ab  = (short*)(ws + 28311552);         // 2 MB   [B,SQ,1024]

  gemm64<0><<<dim3(16, 8), 256, 0, stream>>>(latent, wq, qnw, Qb);
  proj_kv<<<dim3(64, 2, 2), 256, 0, stream>>>(inputs, wk, wv, knw, Kb, Vtb);
  attn_kernel<<<256 * NSPLIT, 256, 0, stream>>>(Qb, Kb, Vtb, Op, Ml);
  merge_attn<<<RB * 64 / 256, 256, 0, stream>>>(Op, Ml, Ab);
  gemm64<1><<<dim3(16, 8), 256, 0, stream>>>(Ab, wo, nullptr, (float*)d_out);
}

// Round 9
// 232.785 us; speedup vs baseline: 1.5918x; 1.0345x over previous
//
#include <hip/hip_runtime.h>

#define NB 2
#define SQ 512
#define SKV 4096
#define HID 1024
#define NH 16
#define NHK 4
#define NG 4
#define HD 64
#define EPSF 1e-6f
#define NSPLIT 4
#define RB (NB * NH * SQ)  // 16384 total q-rows

typedef short v8s __attribute__((ext_vector_type(8)));
typedef short v4s __attribute__((ext_vector_type(4)));
typedef float v4f __attribute__((ext_vector_type(4)));
typedef float v2f __attribute__((ext_vector_type(2)));

// HW RTNE f32->bf16 (compiler packs pairs into v_cvt_pk_bf16_f32; identical
// rounding to the 0x7FFF+lsb bit-trick for normal values)
static __device__ __forceinline__ short f2bf(float f) {
  __bf16 b = (__bf16)f;
  return (short)__builtin_bit_cast(unsigned short, b);
}

// swizzled LDS fragment read: row-major [R][64] bf16 tile, 128B rows,
// byte ^= (row&7)<<4  (conflict-free for 16-row x 4-group b128 reads)
static __device__ __forceinline__ v8s lds_frag(const short* lds, int row, int kbyte) {
  return *(const v8s*)((const char*)lds + row * 128 + (kbyte ^ ((row & 7) << 4)));
}

// stage a (NIT*32)x64 tile (rows r0.., cols c0..) into swizzled LDS; f32->bf16 if SRC_F32
template<int SRC_F32, int NIT>
static __device__ __forceinline__ void stage_tile(const void* src, int ld,
                                                  int r0, int c0, short* lds, int t) {
#pragma unroll
  for (int i = 0; i < NIT; ++i) {
    int flat = t * 8 + i * 2048;
    int row = flat >> 6, col = flat & 63;
    v8s v;
    if (SRC_F32) {
      const float* p = (const float*)src + (size_t)(r0 + row) * ld + c0 + col;
      v4f a = *(const v4f*)p;
      v4f b = *(const v4f*)(p + 4);
      v[0] = f2bf(a[0]); v[1] = f2bf(a[1]); v[2] = f2bf(a[2]); v[3] = f2bf(a[3]);
      v[4] = f2bf(b[0]); v[5] = f2bf(b[1]); v[6] = f2bf(b[2]); v[7] = f2bf(b[3]);
    } else {
      v = *(const v8s*)((const short*)src + (size_t)(r0 + row) * ld + c0 + col);
    }
    *(v8s*)((char*)lds + row * 128 + ((col * 2) ^ ((row & 7) << 4))) = v;
  }
}

// Unified Q/K/V projection, one launch, 640 blocks:
//  blocks [0,512):  K/V — z=bid&1 (0:K,1:V), head=(bid>>1)&3, mblk=bid>>3. BM=128,BN=64.
//  blocks [512,640): Q  — r=bid-512, mblk=r&15, nblk=r>>4. BM=64, BN=128 (2 heads).
// All: 4 waves, each owns 32 rows x 64 cols (mf 2, nf 4, 16 MFMA/k-step).
// K/Q: in-register rmsnorm epilogue (16-lane reduce). V: transposed write.
__global__ __launch_bounds__(256) void proj_all(const float* __restrict__ inputs,
                                                const float* __restrict__ latent,
                                                const float* __restrict__ wq,
                                                const float* __restrict__ wk,
                                                const float* __restrict__ wv,
                                                const float* __restrict__ qnw,
                                                const float* __restrict__ knw,
                                                short* __restrict__ Qb,
                                                short* __restrict__ Kb,
                                                short* __restrict__ Vtb) {
  __shared__ __align__(16) short Asm[128 * 64];
  __shared__ __align__(16) short Bsm[128 * 64];
  const int bid = blockIdx.x;
  const int t = threadIdx.x, lane = t & 63, w = t >> 6;
  const int l15 = lane & 15, g4 = lane >> 4;
  v4f acc[2][4] = {};

  if (bid < 512) {  // ---- K/V branch ----
    const int z = bid & 1, head = (bid >> 1) & 3, mblk = bid >> 3;
    const int m0 = mblk * 128;
    const float* W = z ? wv : wk;
    for (int k0 = 0; k0 < HID; k0 += 64) {
      __syncthreads();
      stage_tile<1, 4>(inputs, HID, m0, k0, Asm, t);
      stage_tile<1, 2>(W, HID, head * 64, k0, Bsm, t);
      __syncthreads();
      v8s af[2][2], bfr[4][2];
#pragma unroll
      for (int mf = 0; mf < 2; ++mf)
#pragma unroll
        for (int s = 0; s < 2; ++s)
          af[mf][s] = lds_frag(Asm, w * 32 + mf * 16 + l15, s * 64 + g4 * 16);
#pragma unroll
      for (int nf = 0; nf < 4; ++nf)
#pragma unroll
        for (int s = 0; s < 2; ++s)
          bfr[nf][s] = lds_frag(Bsm, nf * 16 + l15, s * 64 + g4 * 16);
#pragma unroll
      for (int mf = 0; mf < 2; ++mf)
#pragma unroll
        for (int nf = 0; nf < 4; ++nf)
#pragma unroll
          for (int s = 0; s < 2; ++s)
            acc[mf][nf] = __builtin_amdgcn_mfma_f32_16x16x32_bf16(af[mf][s], bfr[nf][s],
                                                                  acc[mf][nf], 0, 0, 0);
    }
    if (!z) {  // K: rmsnorm -> Kb [B,NHK,SKV,64]
      float wcol[4];
#pragma unroll
      for (int nf = 0; nf < 4; ++nf) wcol[nf] = knw[nf * 16 + l15];
#pragma unroll
      for (int mf = 0; mf < 2; ++mf)
#pragma unroll
        for (int j = 0; j < 4; ++j) {
          float ss = acc[mf][0][j] * acc[mf][0][j] + acc[mf][1][j] * acc[mf][1][j] +
                     acc[mf][2][j] * acc[mf][2][j] + acc[mf][3][j] * acc[mf][3][j];
#pragma unroll
          for (int msk = 1; msk < 16; msk <<= 1) ss += __shfl_xor(ss, msk);
          float sc = rsqrtf(ss * (1.0f / 64.0f) + EPSF);
          int m = m0 + w * 32 + mf * 16 + g4 * 4 + j;
          int b = m >> 12, sl = m & (SKV - 1);
          size_t base = ((size_t)(b * NHK + head) * SKV + sl) * 64;
#pragma unroll
          for (int nf = 0; nf < 4; ++nf)
            Kb[base + nf * 16 + l15] = f2bf(acc[mf][nf][j] * sc * wcol[nf]);
        }
    } else {  // V: transposed -> Vtb [B,NHK,64,SKV]
#pragma unroll
      for (int mf = 0; mf < 2; ++mf) {
        int m = m0 + w * 32 + mf * 16 + g4 * 4;
        int b = m >> 12, sl = m & (SKV - 1);
#pragma unroll
        for (int nf = 0; nf < 4; ++nf) {
          int d = nf * 16 + l15;
          v4s o;
#pragma unroll
          for (int j = 0; j < 4; ++j) o[j] = f2bf(acc[mf][nf][j]);
          *(v4s*)(Vtb + ((size_t)(b * NHK + head) * 64 + d) * SKV + sl) = o;
        }
      }
    }
  } else {  // ---- Q branch ----
    const int r = bid - 512;
    const int mblk = r & 15, nblk = r >> 4;
    const int m0 = mblk * 64;
    const int wr = w >> 1, wc = w & 1;
    for (int k0 = 0; k0 < HID; k0 += 64) {
      __syncthreads();
      stage_tile<1, 2>(latent, HID, m0, k0, Asm, t);
      stage_tile<1, 4>(wq, HID, nblk * 128, k0, Bsm, t);
      __syncthreads();
      v8s af[2][2], bfr[4][2];
#pragma unroll
      for (int mf = 0; mf < 2; ++mf)
#pragma unroll
        for (int s = 0; s < 2; ++s)
          af[mf][s] = lds_frag(Asm, wr * 32 + mf * 16 + l15, s * 64 + g4 * 16);
#pragma unroll
      for (int nf = 0; nf < 4; ++nf)
#pragma unroll
        for (int s = 0; s < 2; ++s)
          bfr[nf][s] = lds_frag(Bsm, wc * 64 + nf * 16 + l15, s * 64 + g4 * 16);
#pragma unroll
      for (int mf = 0; mf < 2; ++mf)
#pragma unroll
        for (int nf = 0; nf < 4; ++nf)
#pragma unroll
          for (int s = 0; s < 2; ++s)
            acc[mf][nf] = __builtin_amdgcn_mfma_f32_16x16x32_bf16(af[mf][s], bfr[nf][s],
                                                                  acc[mf][nf], 0, 0, 0);
    }
    const int head = nblk * 2 + wc;
    float wcol[4];
#pragma unroll
    for (int nf = 0; nf < 4; ++nf) wcol[nf] = qnw[nf * 16 + l15];
#pragma unroll
    for (int mf = 0; mf < 2; ++mf)
#pragma unroll
      for (int j = 0; j < 4; ++j) {
        float ss = acc[mf][0][j] * acc[mf][0][j] + acc[mf][1][j] * acc[mf][1][j] +
                   acc[mf][2][j] * acc[mf][2][j] + acc[mf][3][j] * acc[mf][3][j];
#pragma unroll
        for (int msk = 1; msk < 16; msk <<= 1) ss += __shfl_xor(ss, msk);
        float sc = rsqrtf(ss * (1.0f / 64.0f) + EPSF);
        int m = m0 + wr * 32 + mf * 16 + g4 * 4 + j;
        int b = m >> 9, sl = m & (SQ - 1);
        size_t base = ((size_t)(b * NH + head) * SQ + sl) * 64;
#pragma unroll
        for (int nf = 0; nf < 4; ++nf)
          Qb[base + nf * 16 + l15] = f2bf(acc[mf][nf][j] * sc * wcol[nf]);
      }
  }
}

// WO gemm, K-split x4: partial[ks] = Ab[.,ks*256..+256] @ wo^T chunk. grid (16,8,4).
// BM=64, BN=128, 4 waves 2x2, wave owns 32x64. Partials f32 -> Wop[ks][1024][1024].
__global__ __launch_bounds__(256) void wo_gemm(const short* __restrict__ Ab,
                                               const float* __restrict__ Wo,
                                               float* __restrict__ Wop) {
  __shared__ __align__(16) short Asm[64 * 64];
  __shared__ __align__(16) short Bsm[128 * 64];
  const int t = threadIdx.x, lane = t & 63, w = t >> 6;
  const int l15 = lane & 15, g4 = lane >> 4;
  const int wr = w >> 1, wc = w & 1;
  const int m0 = blockIdx.x * 64, n0 = blockIdx.y * 128, ks = blockIdx.z;
  v4f acc[2][4] = {};
  for (int kk = 0; kk < 4; ++kk) {
    int k0 = ks * 256 + kk * 64;
    __syncthreads();
    stage_tile<0, 2>(Ab, HID, m0, k0, Asm, t);
    stage_tile<1, 4>(Wo, HID, n0, k0, Bsm, t);
    __syncthreads();
    v8s af[2][2], bfr[4][2];
#pragma unroll
    for (int mf = 0; mf < 2; ++mf)
#pragma unroll
      for (int s = 0; s < 2; ++s)
        af[mf][s] = lds_frag(Asm, wr * 32 + mf * 16 + l15, s * 64 + g4 * 16);
#pragma unroll
    for (int nf = 0; nf < 4; ++nf)
#pragma unroll
      for (int s = 0; s < 2; ++s)
        bfr[nf][s] = lds_frag(Bsm, wc * 64 + nf * 16 + l15, s * 64 + g4 * 16);
#pragma unroll
    for (int mf = 0; mf < 2; ++mf)
#pragma unroll
      for (int nf = 0; nf < 4; ++nf)
#pragma unroll
        for (int s = 0; s < 2; ++s)
          acc[mf][nf] = __builtin_amdgcn_mfma_f32_16x16x32_bf16(af[mf][s], bfr[nf][s],
                                                                acc[mf][nf], 0, 0, 0);
  }
  float* C = Wop + (size_t)ks * HID * NB * SQ;
#pragma unroll
  for (int mf = 0; mf < 2; ++mf)
#pragma unroll
    for (int j = 0; j < 4; ++j) {
      int m = m0 + wr * 32 + mf * 16 + g4 * 4 + j;
#pragma unroll
      for (int nf = 0; nf < 4; ++nf)
        C[(size_t)m * HID + n0 + wc * 64 + nf * 16 + l15] = acc[mf][nf][j];
    }
}

// Sum 4 K-split partials -> d_out f32
__global__ __launch_bounds__(256) void wo_reduce(const float* __restrict__ Wop,
                                                 float* __restrict__ out) {
  int idx = (blockIdx.x * 256 + threadIdx.x) * 4;
  v4f s = *(const v4f*)(Wop + idx);
#pragma unroll
  for (int ks = 1; ks < 4; ++ks) {
    v4f p = *(const v4f*)(Wop + (size_t)ks * HID * NB * SQ + idx);
    s[0] += p[0]; s[1] += p[1]; s[2] += p[2]; s[3] += p[3];
  }
  *(v4f*)(out + idx) = s;
}

// Flash attention, KV-split, KVBLK=128 (two 64-tiles per barrier pair, batched softmax).
// block = (split, b, hk, qt16); 4 waves = 4 GQA heads sharing K/V tiles.  (UNCHANGED)
__global__ __launch_bounds__(256) void attn_kernel(const short* __restrict__ Qb,
                                                   const short* __restrict__ Kb,
                                                   const short* __restrict__ Vt,
                                                   float* __restrict__ Op,
                                                   float* __restrict__ Ml) {
  __shared__ __align__(16) short Ksm[2][64 * 64];
  __shared__ __align__(16) short Vsm[2][64 * 64];
  __shared__ __align__(16) short Psm[4][16 * 64];
  int id = blockIdx.x;
  int qt = id & 31, hk = (id >> 5) & 3, b = (id >> 7) & 1, sp = id >> 8;
  int t = threadIdx.x, w = t >> 6, lane = t & 63;
  int l15 = lane & 15, g4 = lane >> 4;
  int h = hk * NG + w;

  const short* qbase = Qb + (((size_t)(b * NH + h)) * SQ + qt * 16) * 64;
  v8s aq[2];
#pragma unroll
  for (int s = 0; s < 2; ++s)
    aq[s] = *(const v8s*)(qbase + (size_t)l15 * 64 + s * 32 + g4 * 8);

  const short* kbase = Kb + ((size_t)(b * NHK + hk)) * SKV * 64;
  const short* vbase = Vt + ((size_t)(b * NHK + hk)) * 64 * SKV;
  char* pbase = (char*)&Psm[w][0];

  v4f acco[4] = {};
  float mrow[4], lrow[4];
#pragma unroll
  for (int r = 0; r < 4; ++r) { mrow[r] = -__builtin_inff(); lrow[r] = 0.f; }

  const int KV0 = sp * (SKV / NSPLIT);
  for (int kt = 0; kt < SKV / NSPLIT / 128; ++kt) {
    int kv0 = KV0 + kt * 128;
    __syncthreads();
    stage_tile<0, 2>(kbase, 64, kv0, 0, Ksm[0], t);
    stage_tile<0, 2>(kbase, 64, kv0 + 64, 0, Ksm[1], t);
    stage_tile<0, 2>(vbase, SKV, 0, kv0, Vsm[0], t);
    stage_tile<0, 2>(vbase, SKV, 0, kv0 + 64, Vsm[1], t);
    __syncthreads();

    v4f accs[8] = {};
#pragma unroll
    for (int hf = 0; hf < 2; ++hf)
#pragma unroll
      for (int f = 0; f < 4; ++f)
#pragma unroll
        for (int s = 0; s < 2; ++s) {
          v8s bk = lds_frag(Ksm[hf], f * 16 + l15, s * 64 + g4 * 16);
          accs[hf * 4 + f] =
              __builtin_amdgcn_mfma_f32_16x16x32_bf16(aq[s], bk, accs[hf * 4 + f], 0, 0, 0);
        }

    float tm[4];
#pragma unroll
    for (int r = 0; r < 4; ++r) {
      float m01 = fmaxf(accs[0][r], accs[1][r]), m23 = fmaxf(accs[2][r], accs[3][r]);
      float m45 = fmaxf(accs[4][r], accs[5][r]), m67 = fmaxf(accs[6][r], accs[7][r]);
      tm[r] = fmaxf(fmaxf(m01, m23), fmaxf(m45, m67));
    }
#pragma unroll
    for (int msk = 1; msk < 16; msk <<= 1)
#pragma unroll
      for (int r = 0; r < 4; ++r)
        tm[r] = fmaxf(tm[r], __shfl_xor(tm[r], msk));
    float al[4];
#pragma unroll
    for (int r = 0; r < 4; ++r) {
      float mn = fmaxf(mrow[r], tm[r]);
      al[r] = __expf(mrow[r] - mn);
      mrow[r] = mn;
    }
    float rs[4] = {0.f, 0.f, 0.f, 0.f};
#pragma unroll
    for (int f = 0; f < 8; ++f)
#pragma unroll
      for (int r = 0; r < 4; ++r) {
        accs[f][r] = __expf(accs[f][r] - mrow[r]);
        rs[r] += accs[f][r];
      }
#pragma unroll
    for (int msk = 1; msk < 16; msk <<= 1)
#pragma unroll
      for (int r = 0; r < 4; ++r) rs[r] += __shfl_xor(rs[r], msk);
#pragma unroll
    for (int r = 0; r < 4; ++r) lrow[r] = lrow[r] * al[r] + rs[r];
#pragma unroll
    for (int fd = 0; fd < 4; ++fd)
#pragma unroll
      for (int r = 0; r < 4; ++r) acco[fd][r] *= al[r];

#pragma unroll
    for (int hf = 0; hf < 2; ++hf) {
#pragma unroll
      for (int f = 0; f < 4; ++f)
#pragma unroll
        for (int r = 0; r < 4; ++r) {
          int row = g4 * 4 + r;
          int colB = (f * 16 + l15) * 2;
          *(short*)(pbase + row * 128 + (colB ^ ((row & 7) << 4))) = f2bf(accs[hf * 4 + f][r]);
        }
      asm volatile("s_waitcnt lgkmcnt(0)" ::: "memory");
      __builtin_amdgcn_sched_barrier(0);
      v8s pa[2];
#pragma unroll
      for (int s = 0; s < 2; ++s)
        pa[s] = *(const v8s*)(pbase + l15 * 128 + ((s * 64 + g4 * 16) ^ ((l15 & 7) << 4)));
      asm volatile("s_waitcnt lgkmcnt(0)" ::: "memory");
      __builtin_amdgcn_sched_barrier(0);
#pragma unroll
      for (int fd = 0; fd < 4; ++fd)
#pragma unroll
        for (int s = 0; s < 2; ++s) {
          v8s vb = lds_frag(Vsm[hf], fd * 16 + l15, s * 64 + g4 * 16);
          acco[fd] = __builtin_amdgcn_mfma_f32_16x16x32_bf16(pa[s], vb, acco[fd], 0, 0, 0);
        }
    }
  }

  size_t rowbase = ((size_t)b * NH + h) * SQ + qt * 16;
#pragma unroll
  for (int fd = 0; fd < 4; ++fd)
#pragma unroll
    for (int r = 0; r < 4; ++r) {
      int row = g4 * 4 + r;
      Op[((size_t)sp * RB + rowbase + row) * 64 + fd * 16 + l15] = acco[fd][r];
    }
  if (l15 == 0) {
#pragma unroll
    for (int r = 0; r < 4; ++r) {
      int row = g4 * 4 + r;
      v2f ml; ml[0] = mrow[r]; ml[1] = lrow[r];
      *(v2f*)(Ml + ((size_t)sp * RB + rowbase + row) * 2) = ml;
    }
  }
}

// Merge NSPLIT partials -> Ab bf16 [B, SQ, H*64]
__global__ __launch_bounds__(256) void merge_attn(const float* __restrict__ Op,
                                                  const float* __restrict__ Ml,
                                                  short* __restrict__ Ab) {
  int idx = blockIdx.x * 256 + threadIdx.x;  // RB*64 total
  int d = idx & 63, row = idx >> 6;
  float ms[NSPLIT], ls[NSPLIT];
  float M = -__builtin_inff();
#pragma unroll
  for (int s = 0; s < NSPLIT; ++s) {
    v2f ml = *(const v2f*)(Ml + ((size_t)s * RB + row) * 2);
    ms[s] = ml[0]; ls[s] = ml[1];
    M = fmaxf(M, ms[s]);
  }
  float L = 0.f, o = 0.f;
#pragma unroll
  for (int s = 0; s < NSPLIT; ++s) {
    float wgt = __expf(ms[s] - M);
    L += ls[s] * wgt;
    o += wgt * Op[((size_t)s * RB + row) * 64 + d];
  }
  int b = row >> 13;
  int hh = (row >> 9) & 15;
  int sq = row & 511;
  Ab[((size_t)(b * SQ + sq)) * HID + hh * 64 + d] = f2bf(o / L);
}

extern "C" void kernel_launch(void* const* d_in, const int* in_sizes, int n_in,
                              void* d_out, int out_size, void* d_ws, size_t ws_size,
                              hipStream_t stream) {
  const float* inputs = (const float*)d_in[0];  // [B,SKV,1024]
  const float* latent = (const float*)d_in[1];  // [B,SQ,1024]
  const float* wq = (const float*)d_in[2];      // [1024,1024]
  const float* wk = (const float*)d_in[3];      // [256,1024]
  const float* wv = (const float*)d_in[4];      // [256,1024]
  const float* wo = (const float*)d_in[5];      // [1024,1024]
  const float* qnw = (const float*)d_in[6];     // [64]
  const float* knw = (const float*)d_in[7];     // [64]

  char* ws = (char*)d_ws;
  float* Op  = (float*)(ws);                    // 16 MB  [NSPLIT, RB, 64] (dead after merge)
  float* Wop = (float*)(ws);                    // 16 MB  [4,1024,1024] wo partials (reuses Op)
  float* Ml  = (float*)(ws + 16777216);         // 0.5 MB [NSPLIT, RB, 2]
  short* Qb  = (short*)(ws + 17825792);         // 2 MB   [B,NH,SQ,64]
  short* Kb  = (short*)(ws + 19922944);         // 4 MB   [B,NHK,SKV,64]
  short* Vtb = (short*)(ws + 24117248);         // 4 MB   [B,NHK,64,SKV]
  short* Ab  = (short*)(ws + 28311552);         // 2 MB   [B,SQ,1024]

  proj_all<<<640, 256, 0, stream>>>(inputs, latent, wq, wk, wv, qnw, knw, Qb, Kb, Vtb);
  attn_kernel<<<256 * NSPLIT, 256, 0, stream>>>(Qb, Kb, Vtb, Op, Ml);
  merge_attn<<<RB * 64 / 256, 256, 0, stream>>>(Op, Ml, Ab);
  wo_gemm<<<dim3(16, 8, 4), 256, 0, stream>>>(Ab, wo, Wop);
  wo_reduce<<<1024, 256, 0, stream>>>(Wop, (float*)d_out);
}

// Round 10
// 218.129 us; speedup vs baseline: 1.6988x; 1.0672x over previous
//
#include <hip/hip_runtime.h>

#define NB 2
#define SQ 512
#define SKV 4096
#define HID 1024
#define NH 16
#define NHK 4
#define NG 4
#define HD 64
#define EPSF 1e-6f
#define NSPLIT 4
#define RB (NB * NH * SQ)  // 16384 total q-rows

typedef short v8s __attribute__((ext_vector_type(8)));
typedef short v4s __attribute__((ext_vector_type(4)));
typedef float v4f __attribute__((ext_vector_type(4)));
typedef float v2f __attribute__((ext_vector_type(2)));

// branchless RTNE f32->bf16 bit-trick. NOT the (__bf16) HW cast: that emits a
// NaN-correct v_cmp/v_cndmask pair per element which serializes on VCC —
// measured +21us on attn_kernel (r8->r9 A/B, 61->82.5us).
static __device__ __forceinline__ short f2bf(float f) {
  unsigned u = __builtin_bit_cast(unsigned, f);
  u += 0x7FFFu + ((u >> 16) & 1u);
  return (short)(u >> 16);
}

// swizzled LDS fragment read: row-major [R][64] bf16 tile, 128B rows,
// byte ^= (row&7)<<4  (conflict-free for 16-row x 4-group b128 reads)
static __device__ __forceinline__ v8s lds_frag(const short* lds, int row, int kbyte) {
  return *(const v8s*)((const char*)lds + row * 128 + (kbyte ^ ((row & 7) << 4)));
}

// stage a (NIT*32)x64 tile (rows r0.., cols c0..) into swizzled LDS; f32->bf16 if SRC_F32
template<int SRC_F32, int NIT>
static __device__ __forceinline__ void stage_tile(const void* src, int ld,
                                                  int r0, int c0, short* lds, int t) {
#pragma unroll
  for (int i = 0; i < NIT; ++i) {
    int flat = t * 8 + i * 2048;
    int row = flat >> 6, col = flat & 63;
    v8s v;
    if (SRC_F32) {
      const float* p = (const float*)src + (size_t)(r0 + row) * ld + c0 + col;
      v4f a = *(const v4f*)p;
      v4f b = *(const v4f*)(p + 4);
      v[0] = f2bf(a[0]); v[1] = f2bf(a[1]); v[2] = f2bf(a[2]); v[3] = f2bf(a[3]);
      v[4] = f2bf(b[0]); v[5] = f2bf(b[1]); v[6] = f2bf(b[2]); v[7] = f2bf(b[3]);
    } else {
      v = *(const v8s*)((const short*)src + (size_t)(r0 + row) * ld + c0 + col);
    }
    *(v8s*)((char*)lds + row * 128 + ((col * 2) ^ ((row & 7) << 4))) = v;
  }
}

// Unified Q/K/V projection, one launch, 640 blocks:
//  blocks [0,512):  K/V — z=bid&1 (0:K,1:V), head=(bid>>1)&3, mblk=bid>>3. BM=128,BN=64.
//  blocks [512,640): Q  — r=bid-512, mblk=r&15, nblk=r>>4. BM=64, BN=128 (2 heads).
// All: 4 waves, each owns 32 rows x 64 cols (mf 2, nf 4, 16 MFMA/k-step).
// K/Q: in-register rmsnorm epilogue (16-lane reduce). V: transposed write.
__global__ __launch_bounds__(256) void proj_all(const float* __restrict__ inputs,
                                                const float* __restrict__ latent,
                                                const float* __restrict__ wq,
                                                const float* __restrict__ wk,
                                                const float* __restrict__ wv,
                                                const float* __restrict__ qnw,
                                                const float* __restrict__ knw,
                                                short* __restrict__ Qb,
                                                short* __restrict__ Kb,
                                                short* __restrict__ Vtb) {
  __shared__ __align__(16) short Asm[128 * 64];
  __shared__ __align__(16) short Bsm[128 * 64];
  const int bid = blockIdx.x;
  const int t = threadIdx.x, lane = t & 63, w = t >> 6;
  const int l15 = lane & 15, g4 = lane >> 4;
  v4f acc[2][4] = {};

  if (bid < 512) {  // ---- K/V branch ----
    const int z = bid & 1, head = (bid >> 1) & 3, mblk = bid >> 3;
    const int m0 = mblk * 128;
    const float* W = z ? wv : wk;
    for (int k0 = 0; k0 < HID; k0 += 64) {
      __syncthreads();
      stage_tile<1, 4>(inputs, HID, m0, k0, Asm, t);
      stage_tile<1, 2>(W, HID, head * 64, k0, Bsm, t);
      __syncthreads();
      v8s af[2][2], bfr[4][2];
#pragma unroll
      for (int mf = 0; mf < 2; ++mf)
#pragma unroll
        for (int s = 0; s < 2; ++s)
          af[mf][s] = lds_frag(Asm, w * 32 + mf * 16 + l15, s * 64 + g4 * 16);
#pragma unroll
      for (int nf = 0; nf < 4; ++nf)
#pragma unroll
        for (int s = 0; s < 2; ++s)
          bfr[nf][s] = lds_frag(Bsm, nf * 16 + l15, s * 64 + g4 * 16);
#pragma unroll
      for (int mf = 0; mf < 2; ++mf)
#pragma unroll
        for (int nf = 0; nf < 4; ++nf)
#pragma unroll
          for (int s = 0; s < 2; ++s)
            acc[mf][nf] = __builtin_amdgcn_mfma_f32_16x16x32_bf16(af[mf][s], bfr[nf][s],
                                                                  acc[mf][nf], 0, 0, 0);
    }
    if (!z) {  // K: rmsnorm -> Kb [B,NHK,SKV,64]
      float wcol[4];
#pragma unroll
      for (int nf = 0; nf < 4; ++nf) wcol[nf] = knw[nf * 16 + l15];
#pragma unroll
      for (int mf = 0; mf < 2; ++mf)
#pragma unroll
        for (int j = 0; j < 4; ++j) {
          float ss = acc[mf][0][j] * acc[mf][0][j] + acc[mf][1][j] * acc[mf][1][j] +
                     acc[mf][2][j] * acc[mf][2][j] + acc[mf][3][j] * acc[mf][3][j];
#pragma unroll
          for (int msk = 1; msk < 16; msk <<= 1) ss += __shfl_xor(ss, msk);
          float sc = rsqrtf(ss * (1.0f / 64.0f) + EPSF);
          int m = m0 + w * 32 + mf * 16 + g4 * 4 + j;
          int b = m >> 12, sl = m & (SKV - 1);
          size_t base = ((size_t)(b * NHK + head) * SKV + sl) * 64;
#pragma unroll
          for (int nf = 0; nf < 4; ++nf)
            Kb[base + nf * 16 + l15] = f2bf(acc[mf][nf][j] * sc * wcol[nf]);
        }
    } else {  // V: transposed -> Vtb [B,NHK,64,SKV]
#pragma unroll
      for (int mf = 0; mf < 2; ++mf) {
        int m = m0 + w * 32 + mf * 16 + g4 * 4;
        int b = m >> 12, sl = m & (SKV - 1);
#pragma unroll
        for (int nf = 0; nf < 4; ++nf) {
          int d = nf * 16 + l15;
          v4s o;
#pragma unroll
          for (int j = 0; j < 4; ++j) o[j] = f2bf(acc[mf][nf][j]);
          *(v4s*)(Vtb + ((size_t)(b * NHK + head) * 64 + d) * SKV + sl) = o;
        }
      }
    }
  } else {  // ---- Q branch ----
    const int r = bid - 512;
    const int mblk = r & 15, nblk = r >> 4;
    const int m0 = mblk * 64;
    const int wr = w >> 1, wc = w & 1;
    for (int k0 = 0; k0 < HID; k0 += 64) {
      __syncthreads();
      stage_tile<1, 2>(latent, HID, m0, k0, Asm, t);
      stage_tile<1, 4>(wq, HID, nblk * 128, k0, Bsm, t);
      __syncthreads();
      v8s af[2][2], bfr[4][2];
#pragma unroll
      for (int mf = 0; mf < 2; ++mf)
#pragma unroll
        for (int s = 0; s < 2; ++s)
          af[mf][s] = lds_frag(Asm, wr * 32 + mf * 16 + l15, s * 64 + g4 * 16);
#pragma unroll
      for (int nf = 0; nf < 4; ++nf)
#pragma unroll
        for (int s = 0; s < 2; ++s)
          bfr[nf][s] = lds_frag(Bsm, wc * 64 + nf * 16 + l15, s * 64 + g4 * 16);
#pragma unroll
      for (int mf = 0; mf < 2; ++mf)
#pragma unroll
        for (int nf = 0; nf < 4; ++nf)
#pragma unroll
          for (int s = 0; s < 2; ++s)
            acc[mf][nf] = __builtin_amdgcn_mfma_f32_16x16x32_bf16(af[mf][s], bfr[nf][s],
                                                                  acc[mf][nf], 0, 0, 0);
    }
    const int head = nblk * 2 + wc;
    float wcol[4];
#pragma unroll
    for (int nf = 0; nf < 4; ++nf) wcol[nf] = qnw[nf * 16 + l15];
#pragma unroll
    for (int mf = 0; mf < 2; ++mf)
#pragma unroll
      for (int j = 0; j < 4; ++j) {
        float ss = acc[mf][0][j] * acc[mf][0][j] + acc[mf][1][j] * acc[mf][1][j] +
                   acc[mf][2][j] * acc[mf][2][j] + acc[mf][3][j] * acc[mf][3][j];
#pragma unroll
        for (int msk = 1; msk < 16; msk <<= 1) ss += __shfl_xor(ss, msk);
        float sc = rsqrtf(ss * (1.0f / 64.0f) + EPSF);
        int m = m0 + wr * 32 + mf * 16 + g4 * 4 + j;
        int b = m >> 9, sl = m & (SQ - 1);
        size_t base = ((size_t)(b * NH + head) * SQ + sl) * 64;
#pragma unroll
        for (int nf = 0; nf < 4; ++nf)
          Qb[base + nf * 16 + l15] = f2bf(acc[mf][nf][j] * sc * wcol[nf]);
      }
  }
}

// WO gemm, K-split x4: partial[ks] = Ab[.,ks*256..+256] @ wo^T chunk. grid (16,8,4).
// BM=64, BN=128, 4 waves 2x2, wave owns 32x64. Partials f32 -> Wop[ks][1024][1024].
__global__ __launch_bounds__(256) void wo_gemm(const short* __restrict__ Ab,
                                               const float* __restrict__ Wo,
                                               float* __restrict__ Wop) {
  __shared__ __align__(16) short Asm[64 * 64];
  __shared__ __align__(16) short Bsm[128 * 64];
  const int t = threadIdx.x, lane = t & 63, w = t >> 6;
  const int l15 = lane & 15, g4 = lane >> 4;
  const int wr = w >> 1, wc = w & 1;
  const int m0 = blockIdx.x * 64, n0 = blockIdx.y * 128, ks = blockIdx.z;
  v4f acc[2][4] = {};
  for (int kk = 0; kk < 4; ++kk) {
    int k0 = ks * 256 + kk * 64;
    __syncthreads();
    stage_tile<0, 2>(Ab, HID, m0, k0, Asm, t);
    stage_tile<1, 4>(Wo, HID, n0, k0, Bsm, t);
    __syncthreads();
    v8s af[2][2], bfr[4][2];
#pragma unroll
    for (int mf = 0; mf < 2; ++mf)
#pragma unroll
      for (int s = 0; s < 2; ++s)
        af[mf][s] = lds_frag(Asm, wr * 32 + mf * 16 + l15, s * 64 + g4 * 16);
#pragma unroll
    for (int nf = 0; nf < 4; ++nf)
#pragma unroll
      for (int s = 0; s < 2; ++s)
        bfr[nf][s] = lds_frag(Bsm, wc * 64 + nf * 16 + l15, s * 64 + g4 * 16);
#pragma unroll
    for (int mf = 0; mf < 2; ++mf)
#pragma unroll
      for (int nf = 0; nf < 4; ++nf)
#pragma unroll
        for (int s = 0; s < 2; ++s)
          acc[mf][nf] = __builtin_amdgcn_mfma_f32_16x16x32_bf16(af[mf][s], bfr[nf][s],
                                                                acc[mf][nf], 0, 0, 0);
  }
  float* C = Wop + (size_t)ks * HID * NB * SQ;
#pragma unroll
  for (int mf = 0; mf < 2; ++mf)
#pragma unroll
    for (int j = 0; j < 4; ++j) {
      int m = m0 + wr * 32 + mf * 16 + g4 * 4 + j;
#pragma unroll
      for (int nf = 0; nf < 4; ++nf)
        C[(size_t)m * HID + n0 + wc * 64 + nf * 16 + l15] = acc[mf][nf][j];
    }
}

// Sum 4 K-split partials -> d_out f32
__global__ __launch_bounds__(256) void wo_reduce(const float* __restrict__ Wop,
                                                 float* __restrict__ out) {
  int idx = (blockIdx.x * 256 + threadIdx.x) * 4;
  v4f s = *(const v4f*)(Wop + idx);
#pragma unroll
  for (int ks = 1; ks < 4; ++ks) {
    v4f p = *(const v4f*)(Wop + (size_t)ks * HID * NB * SQ + idx);
    s[0] += p[0]; s[1] += p[1]; s[2] += p[2]; s[3] += p[3];
  }
  *(v4f*)(out + idx) = s;
}

// Flash attention, KV-split, KVBLK=128 (two 64-tiles per barrier pair, batched softmax).
// block = (split, b, hk, qt16); 4 waves = 4 GQA heads sharing K/V tiles.
__global__ __launch_bounds__(256) void attn_kernel(const short* __restrict__ Qb,
                                                   const short* __restrict__ Kb,
                                                   const short* __restrict__ Vt,
                                                   float* __restrict__ Op,
                                                   float* __restrict__ Ml) {
  __shared__ __align__(16) short Ksm[2][64 * 64];
  __shared__ __align__(16) short Vsm[2][64 * 64];
  __shared__ __align__(16) short Psm[4][16 * 64];
  int id = blockIdx.x;
  int qt = id & 31, hk = (id >> 5) & 3, b = (id >> 7) & 1, sp = id >> 8;
  int t = threadIdx.x, w = t >> 6, lane = t & 63;
  int l15 = lane & 15, g4 = lane >> 4;
  int h = hk * NG + w;

  const short* qbase = Qb + (((size_t)(b * NH + h)) * SQ + qt * 16) * 64;
  v8s aq[2];
#pragma unroll
  for (int s = 0; s < 2; ++s)
    aq[s] = *(const v8s*)(qbase + (size_t)l15 * 64 + s * 32 + g4 * 8);

  const short* kbase = Kb + ((size_t)(b * NHK + hk)) * SKV * 64;
  const short* vbase = Vt + ((size_t)(b * NHK + hk)) * 64 * SKV;
  char* pbase = (char*)&Psm[w][0];

  v4f acco[4] = {};
  float mrow[4], lrow[4];
#pragma unroll
  for (int r = 0; r < 4; ++r) { mrow[r] = -__builtin_inff(); lrow[r] = 0.f; }

  const int KV0 = sp * (SKV / NSPLIT);
  for (int kt = 0; kt < SKV / NSPLIT / 128; ++kt) {
    int kv0 = KV0 + kt * 128;
    __syncthreads();
    stage_tile<0, 2>(kbase, 64, kv0, 0, Ksm[0], t);
    stage_tile<0, 2>(kbase, 64, kv0 + 64, 0, Ksm[1], t);
    stage_tile<0, 2>(vbase, SKV, 0, kv0, Vsm[0], t);
    stage_tile<0, 2>(vbase, SKV, 0, kv0 + 64, Vsm[1], t);
    __syncthreads();

    v4f accs[8] = {};
#pragma unroll
    for (int hf = 0; hf < 2; ++hf)
#pragma unroll
      for (int f = 0; f < 4; ++f)
#pragma unroll
        for (int s = 0; s < 2; ++s) {
          v8s bk = lds_frag(Ksm[hf], f * 16 + l15, s * 64 + g4 * 16);
          accs[hf * 4 + f] =
              __builtin_amdgcn_mfma_f32_16x16x32_bf16(aq[s], bk, accs[hf * 4 + f], 0, 0, 0);
        }

    float tm[4];
#pragma unroll
    for (int r = 0; r < 4; ++r) {
      float m01 = fmaxf(accs[0][r], accs[1][r]), m23 = fmaxf(accs[2][r], accs[3][r]);
      float m45 = fmaxf(accs[4][r], accs[5][r]), m67 = fmaxf(accs[6][r], accs[7][r]);
      tm[r] = fmaxf(fmaxf(m01, m23), fmaxf(m45, m67));
    }
#pragma unroll
    for (int msk = 1; msk < 16; msk <<= 1)
#pragma unroll
      for (int r = 0; r < 4; ++r)
        tm[r] = fmaxf(tm[r], __shfl_xor(tm[r], msk));
    float al[4];
#pragma unroll
    for (int r = 0; r < 4; ++r) {
      float mn = fmaxf(mrow[r], tm[r]);
      al[r] = __expf(mrow[r] - mn);
      mrow[r] = mn;
    }
    float rs[4] = {0.f, 0.f, 0.f, 0.f};
#pragma unroll
    for (int f = 0; f < 8; ++f)
#pragma unroll
      for (int r = 0; r < 4; ++r) {
        accs[f][r] = __expf(accs[f][r] - mrow[r]);
        rs[r] += accs[f][r];
      }
#pragma unroll
    for (int msk = 1; msk < 16; msk <<= 1)
#pragma unroll
      for (int r = 0; r < 4; ++r) rs[r] += __shfl_xor(rs[r], msk);
#pragma unroll
    for (int r = 0; r < 4; ++r) lrow[r] = lrow[r] * al[r] + rs[r];
#pragma unroll
    for (int fd = 0; fd < 4; ++fd)
#pragma unroll
      for (int r = 0; r < 4; ++r) acco[fd][r] *= al[r];

#pragma unroll
    for (int hf = 0; hf < 2; ++hf) {
#pragma unroll
      for (int f = 0; f < 4; ++f)
#pragma unroll
        for (int r = 0; r < 4; ++r) {
          int row = g4 * 4 + r;
          int colB = (f * 16 + l15) * 2;
          *(short*)(pbase + row * 128 + (colB ^ ((row & 7) << 4))) = f2bf(accs[hf * 4 + f][r]);
        }
      asm volatile("s_waitcnt lgkmcnt(0)" ::: "memory");
      __builtin_amdgcn_sched_barrier(0);
      v8s pa[2];
#pragma unroll
      for (int s = 0; s < 2; ++s)
        pa[s] = *(const v8s*)(pbase + l15 * 128 + ((s * 64 + g4 * 16) ^ ((l15 & 7) << 4)));
      asm volatile("s_waitcnt lgkmcnt(0)" ::: "memory");
      __builtin_amdgcn_sched_barrier(0);
#pragma unroll
      for (int fd = 0; fd < 4; ++fd)
#pragma unroll
        for (int s = 0; s < 2; ++s) {
          v8s vb = lds_frag(Vsm[hf], fd * 16 + l15, s * 64 + g4 * 16);
          acco[fd] = __builtin_amdgcn_mfma_f32_16x16x32_bf16(pa[s], vb, acco[fd], 0, 0, 0);
        }
    }
  }

  size_t rowbase = ((size_t)b * NH + h) * SQ + qt * 16;
#pragma unroll
  for (int fd = 0; fd < 4; ++fd)
#pragma unroll
    for (int r = 0; r < 4; ++r) {
      int row = g4 * 4 + r;
      Op[((size_t)sp * RB + rowbase + row) * 64 + fd * 16 + l15] = acco[fd][r];
    }
  if (l15 == 0) {
#pragma unroll
    for (int r = 0; r < 4; ++r) {
      int row = g4 * 4 + r;
      v2f ml; ml[0] = mrow[r]; ml[1] = lrow[r];
      *(v2f*)(Ml + ((size_t)sp * RB + rowbase + row) * 2) = ml;
    }
  }
}

// Merge NSPLIT partials -> Ab bf16 [B, SQ, H*64]
__global__ __launch_bounds__(256) void merge_attn(const float* __restrict__ Op,
                                                  const float* __restrict__ Ml,
                                                  short* __restrict__ Ab) {
  int idx = blockIdx.x * 256 + threadIdx.x;  // RB*64 total
  int d = idx & 63, row = idx >> 6;
  float ms[NSPLIT], ls[NSPLIT];
  float M = -__builtin_inff();
#pragma unroll
  for (int s = 0; s < NSPLIT; ++s) {
    v2f ml = *(const v2f*)(Ml + ((size_t)s * RB + row) * 2);
    ms[s] = ml[0]; ls[s] = ml[1];
    M = fmaxf(M, ms[s]);
  }
  float L = 0.f, o = 0.f;
#pragma unroll
  for (int s = 0; s < NSPLIT; ++s) {
    float wgt = __expf(ms[s] - M);
    L += ls[s] * wgt;
    o += wgt * Op[((size_t)s * RB + row) * 64 + d];
  }
  int b = row >> 13;
  int hh = (row >> 9) & 15;
  int sq = row & 511;
  Ab[((size_t)(b * SQ + sq)) * HID + hh * 64 + d] = f2bf(o / L);
}

extern "C" void kernel_launch(void* const* d_in, const int* in_sizes, int n_in,
                              void* d_out, int out_size, void* d_ws, size_t ws_size,
                              hipStream_t stream) {
  const float* inputs = (const float*)d_in[0];  // [B,SKV,1024]
  const float* latent = (const float*)d_in[1];  // [B,SQ,1024]
  const float* wq = (const float*)d_in[2];      // [1024,1024]
  const float* wk = (const float*)d_in[3];      // [256,1024]
  const float* wv = (const float*)d_in[4];      // [256,1024]
  const float* wo = (const float*)d_in[5];      // [1024,1024]
  const float* qnw = (const float*)d_in[6];     // [64]
  const float* knw = (const float*)d_in[7];     // [64]

  char* ws = (char*)d_ws;
  float* Op  = (float*)(ws);                    // 16 MB  [NSPLIT, RB, 64] (dead after merge)
  float* Wop = (float*)(ws);                    // 16 MB  [4,1024,1024] wo partials (reuses Op)
  float* Ml  = (float*)(ws + 16777216);         // 0.5 MB [NSPLIT, RB, 2]
  short* Qb  = (short*)(ws + 17825792);         // 2 MB   [B,NH,SQ,64]
  short* Kb  = (short*)(ws + 19922944);         // 4 MB   [B,NHK,SKV,64]
  short* Vtb = (short*)(ws + 24117248);         // 4 MB   [B,NHK,64,SKV]
  short* Ab  = (short*)(ws + 28311552);         // 2 MB   [B,SQ,1024]

  proj_all<<<640, 256, 0, stream>>>(inputs, latent, wq, wk, wv, qnw, knw, Qb, Kb, Vtb);
  attn_kernel<<<256 * NSPLIT, 256, 0, stream>>>(Qb, Kb, Vtb, Op, Ml);
  merge_attn<<<RB * 64 / 256, 256, 0, stream>>>(Op, Ml, Ab);
  wo_gemm<<<dim3(16, 8, 4), 256, 0, stream>>>(Ab, wo, Wop);
  wo_reduce<<<1024, 256, 0, stream>>>(Wop, (float*)d_out);
}

// Round 11
// 213.932 us; speedup vs baseline: 1.7321x; 1.0196x over previous
//
#include <hip/hip_runtime.h>

#define NB 2
#define SQ 512
#define SKV 4096
#define HID 1024
#define NH 16
#define NHK 4
#define NG 4
#define HD 64
#define EPSF 1e-6f
#define NSPLIT 4
#define RB (NB * NH * SQ)  // 16384 total q-rows

typedef short v8s __attribute__((ext_vector_type(8)));
typedef short v4s __attribute__((ext_vector_type(4)));
typedef float v4f __attribute__((ext_vector_type(4)));
typedef float v2f __attribute__((ext_vector_type(2)));

// branchless RTNE f32->bf16 bit-trick. NOT the (__bf16) HW cast: that emits a
// NaN-correct v_cmp/v_cndmask pair per element which serializes on VCC —
// measured +21us on attn_kernel (r8->r9 A/B, 61->82.5us).
static __device__ __forceinline__ short f2bf(float f) {
  unsigned u = __builtin_bit_cast(unsigned, f);
  u += 0x7FFFu + ((u >> 16) & 1u);
  return (short)(u >> 16);
}

// swizzled LDS fragment read: row-major [R][64] bf16 tile, 128B rows,
// byte ^= (row&7)<<4  (conflict-free for 16-row x 4-group b128 reads)
static __device__ __forceinline__ v8s lds_frag(const short* lds, int row, int kbyte) {
  return *(const v8s*)((const char*)lds + row * 128 + (kbyte ^ ((row & 7) << 4)));
}

// stage a (NIT*32)x64 tile (rows r0.., cols c0..) into swizzled LDS; f32->bf16 if SRC_F32
template<int SRC_F32, int NIT>
static __device__ __forceinline__ void stage_tile(const void* src, int ld,
                                                  int r0, int c0, short* lds, int t) {
#pragma unroll
  for (int i = 0; i < NIT; ++i) {
    int flat = t * 8 + i * 2048;
    int row = flat >> 6, col = flat & 63;
    v8s v;
    if (SRC_F32) {
      const float* p = (const float*)src + (size_t)(r0 + row) * ld + c0 + col;
      v4f a = *(const v4f*)p;
      v4f b = *(const v4f*)(p + 4);
      v[0] = f2bf(a[0]); v[1] = f2bf(a[1]); v[2] = f2bf(a[2]); v[3] = f2bf(a[3]);
      v[4] = f2bf(b[0]); v[5] = f2bf(b[1]); v[6] = f2bf(b[2]); v[7] = f2bf(b[3]);
    } else {
      v = *(const v8s*)((const short*)src + (size_t)(r0 + row) * ld + c0 + col);
    }
    *(v8s*)((char*)lds + row * 128 + ((col * 2) ^ ((row & 7) << 4))) = v;
  }
}

// Unified Q/K/V projection, one launch, 640 blocks. XCD-AWARE WORK MAPPING (r10->r11):
// dispatcher round-robins blockIdx%8 across the 8 XCD L2s, so work is arranged so
// blocks sharing operand panels land on the SAME xcd:
//  K/V blocks [0,512): xcd=bid&7 owns mblk in [xcd*8, xcd*8+8) (4MB inputs slab);
//    slot=bid>>3: mblk=xcd*8+(slot>>3), zh=slot&7 -> the 8 (z,head) variants of one
//    mblk are co-XCD (inputs tile fetched ~once; wk/wv 2MB stay L2-resident).
//  Q blocks [512,640): r=bid-512, xcd=r&7 owns 2 nblk x 8 mblk (wq slab 1MB +
//    latent slab 2MB per XCD).
// All: 4 waves, wave owns 32 rows x 64 cols. K/Q: in-register rmsnorm. V: transposed.
__global__ __launch_bounds__(256) void proj_all(const float* __restrict__ inputs,
                                                const float* __restrict__ latent,
                                                const float* __restrict__ wq,
                                                const float* __restrict__ wk,
                                                const float* __restrict__ wv,
                                                const float* __restrict__ qnw,
                                                const float* __restrict__ knw,
                                                short* __restrict__ Qb,
                                                short* __restrict__ Kb,
                                                short* __restrict__ Vtb) {
  __shared__ __align__(16) short Asm[128 * 64];
  __shared__ __align__(16) short Bsm[128 * 64];
  const int bid = blockIdx.x;
  const int t = threadIdx.x, lane = t & 63, w = t >> 6;
  const int l15 = lane & 15, g4 = lane >> 4;
  v4f acc[2][4] = {};

  if (bid < 512) {  // ---- K/V branch ----
    const int xcd = bid & 7, slot = bid >> 3;
    const int mblk = xcd * 8 + (slot >> 3);
    const int zh = slot & 7;
    const int z = zh & 1, head = zh >> 1;
    const int m0 = mblk * 128;
    const float* W = z ? wv : wk;
    for (int k0 = 0; k0 < HID; k0 += 64) {
      __syncthreads();
      stage_tile<1, 4>(inputs, HID, m0, k0, Asm, t);
      stage_tile<1, 2>(W, HID, head * 64, k0, Bsm, t);
      __syncthreads();
      v8s af[2][2], bfr[4][2];
#pragma unroll
      for (int mf = 0; mf < 2; ++mf)
#pragma unroll
        for (int s = 0; s < 2; ++s)
          af[mf][s] = lds_frag(Asm, w * 32 + mf * 16 + l15, s * 64 + g4 * 16);
#pragma unroll
      for (int nf = 0; nf < 4; ++nf)
#pragma unroll
        for (int s = 0; s < 2; ++s)
          bfr[nf][s] = lds_frag(Bsm, nf * 16 + l15, s * 64 + g4 * 16);
#pragma unroll
      for (int mf = 0; mf < 2; ++mf)
#pragma unroll
        for (int nf = 0; nf < 4; ++nf)
#pragma unroll
          for (int s = 0; s < 2; ++s)
            acc[mf][nf] = __builtin_amdgcn_mfma_f32_16x16x32_bf16(af[mf][s], bfr[nf][s],
                                                                  acc[mf][nf], 0, 0, 0);
    }
    if (!z) {  // K: rmsnorm -> Kb [B,NHK,SKV,64]
      float wcol[4];
#pragma unroll
      for (int nf = 0; nf < 4; ++nf) wcol[nf] = knw[nf * 16 + l15];
#pragma unroll
      for (int mf = 0; mf < 2; ++mf)
#pragma unroll
        for (int j = 0; j < 4; ++j) {
          float ss = acc[mf][0][j] * acc[mf][0][j] + acc[mf][1][j] * acc[mf][1][j] +
                     acc[mf][2][j] * acc[mf][2][j] + acc[mf][3][j] * acc[mf][3][j];
#pragma unroll
          for (int msk = 1; msk < 16; msk <<= 1) ss += __shfl_xor(ss, msk);
          float sc = rsqrtf(ss * (1.0f / 64.0f) + EPSF);
          int m = m0 + w * 32 + mf * 16 + g4 * 4 + j;
          int b = m >> 12, sl = m & (SKV - 1);
          size_t base = ((size_t)(b * NHK + head) * SKV + sl) * 64;
#pragma unroll
          for (int nf = 0; nf < 4; ++nf)
            Kb[base + nf * 16 + l15] = f2bf(acc[mf][nf][j] * sc * wcol[nf]);
        }
    } else {  // V: transposed -> Vtb [B,NHK,64,SKV]
#pragma unroll
      for (int mf = 0; mf < 2; ++mf) {
        int m = m0 + w * 32 + mf * 16 + g4 * 4;
        int b = m >> 12, sl = m & (SKV - 1);
#pragma unroll
        for (int nf = 0; nf < 4; ++nf) {
          int d = nf * 16 + l15;
          v4s o;
#pragma unroll
          for (int j = 0; j < 4; ++j) o[j] = f2bf(acc[mf][nf][j]);
          *(v4s*)(Vtb + ((size_t)(b * NHK + head) * 64 + d) * SKV + sl) = o;
        }
      }
    }
  } else {  // ---- Q branch ----
    const int r = bid - 512;
    const int xcd = r & 7, slot = r >> 3;
    const int nblk = (slot & 1) | ((xcd & 3) << 1);
    const int mblk = ((slot >> 1) & 7) | ((xcd >> 2) << 3);
    const int m0 = mblk * 64;
    const int wr = w >> 1, wc = w & 1;
    for (int k0 = 0; k0 < HID; k0 += 64) {
      __syncthreads();
      stage_tile<1, 2>(latent, HID, m0, k0, Asm, t);
      stage_tile<1, 4>(wq, HID, nblk * 128, k0, Bsm, t);
      __syncthreads();
      v8s af[2][2], bfr[4][2];
#pragma unroll
      for (int mf = 0; mf < 2; ++mf)
#pragma unroll
        for (int s = 0; s < 2; ++s)
          af[mf][s] = lds_frag(Asm, wr * 32 + mf * 16 + l15, s * 64 + g4 * 16);
#pragma unroll
      for (int nf = 0; nf < 4; ++nf)
#pragma unroll
        for (int s = 0; s < 2; ++s)
          bfr[nf][s] = lds_frag(Bsm, wc * 64 + nf * 16 + l15, s * 64 + g4 * 16);
#pragma unroll
      for (int mf = 0; mf < 2; ++mf)
#pragma unroll
        for (int nf = 0; nf < 4; ++nf)
#pragma unroll
          for (int s = 0; s < 2; ++s)
            acc[mf][nf] = __builtin_amdgcn_mfma_f32_16x16x32_bf16(af[mf][s], bfr[nf][s],
                                                                  acc[mf][nf], 0, 0, 0);
    }
    const int head = nblk * 2 + wc;
    float wcol[4];
#pragma unroll
    for (int nf = 0; nf < 4; ++nf) wcol[nf] = qnw[nf * 16 + l15];
#pragma unroll
    for (int mf = 0; mf < 2; ++mf)
#pragma unroll
      for (int j = 0; j < 4; ++j) {
        float ss = acc[mf][0][j] * acc[mf][0][j] + acc[mf][1][j] * acc[mf][1][j] +
                   acc[mf][2][j] * acc[mf][2][j] + acc[mf][3][j] * acc[mf][3][j];
#pragma unroll
        for (int msk = 1; msk < 16; msk <<= 1) ss += __shfl_xor(ss, msk);
        float sc = rsqrtf(ss * (1.0f / 64.0f) + EPSF);
        int m = m0 + wr * 32 + mf * 16 + g4 * 4 + j;
        int b = m >> 9, sl = m & (SQ - 1);
        size_t base = ((size_t)(b * NH + head) * SQ + sl) * 64;
#pragma unroll
        for (int nf = 0; nf < 4; ++nf)
          Qb[base + nf * 16 + l15] = f2bf(acc[mf][nf][j] * sc * wcol[nf]);
      }
  }
}

// WO gemm, K-split x4, XCD-aware: flat 512 blocks, xcd=bid&7=nblk (wo slab 512KB
// stays L2-resident per XCD; Ab 2MB streamed). slot=bid>>3: mblk=slot&15, ks=slot>>4.
// BM=64, BN=128, 4 waves 2x2, wave owns 32x64. Partials f32 -> Wop[ks][1024][1024].
__global__ __launch_bounds__(256) void wo_gemm(const short* __restrict__ Ab,
                                               const float* __restrict__ Wo,
                                               float* __restrict__ Wop) {
  __shared__ __align__(16) short Asm[64 * 64];
  __shared__ __align__(16) short Bsm[128 * 64];
  const int t = threadIdx.x, lane = t & 63, w = t >> 6;
  const int l15 = lane & 15, g4 = lane >> 4;
  const int wr = w >> 1, wc = w & 1;
  const int p = blockIdx.x;
  const int nblk = p & 7, slot = p >> 3;
  const int m0 = (slot & 15) * 64, n0 = nblk * 128, ks = slot >> 4;
  v4f acc[2][4] = {};
  for (int kk = 0; kk < 4; ++kk) {
    int k0 = ks * 256 + kk * 64;
    __syncthreads();
    stage_tile<0, 2>(Ab, HID, m0, k0, Asm, t);
    stage_tile<1, 4>(Wo, HID, n0, k0, Bsm, t);
    __syncthreads();
    v8s af[2][2], bfr[4][2];
#pragma unroll
    for (int mf = 0; mf < 2; ++mf)
#pragma unroll
      for (int s = 0; s < 2; ++s)
        af[mf][s] = lds_frag(Asm, wr * 32 + mf * 16 + l15, s * 64 + g4 * 16);
#pragma unroll
    for (int nf = 0; nf < 4; ++nf)
#pragma unroll
      for (int s = 0; s < 2; ++s)
        bfr[nf][s] = lds_frag(Bsm, wc * 64 + nf * 16 + l15, s * 64 + g4 * 16);
#pragma unroll
    for (int mf = 0; mf < 2; ++mf)
#pragma unroll
      for (int nf = 0; nf < 4; ++nf)
#pragma unroll
        for (int s = 0; s < 2; ++s)
          acc[mf][nf] = __builtin_amdgcn_mfma_f32_16x16x32_bf16(af[mf][s], bfr[nf][s],
                                                                acc[mf][nf], 0, 0, 0);
  }
  float* C = Wop + (size_t)ks * HID * NB * SQ;
#pragma unroll
  for (int mf = 0; mf < 2; ++mf)
#pragma unroll
    for (int j = 0; j < 4; ++j) {
      int m = m0 + wr * 32 + mf * 16 + g4 * 4 + j;
#pragma unroll
      for (int nf = 0; nf < 4; ++nf)
        C[(size_t)m * HID + n0 + wc * 64 + nf * 16 + l15] = acc[mf][nf][j];
    }
}

// Sum 4 K-split partials -> d_out f32
__global__ __launch_bounds__(256) void wo_reduce(const float* __restrict__ Wop,
                                                 float* __restrict__ out) {
  int idx = (blockIdx.x * 256 + threadIdx.x) * 4;
  v4f s = *(const v4f*)(Wop + idx);
#pragma unroll
  for (int ks = 1; ks < 4; ++ks) {
    v4f p = *(const v4f*)(Wop + (size_t)ks * HID * NB * SQ + idx);
    s[0] += p[0]; s[1] += p[1]; s[2] += p[2]; s[3] += p[3];
  }
  *(v4f*)(out + idx) = s;
}

// Flash attention, KV-split, KVBLK=128 (two 64-tiles per barrier pair, batched softmax).
// block = (split, b, hk, qt16); 4 waves = 4 GQA heads sharing K/V tiles.  (UNCHANGED)
__global__ __launch_bounds__(256) void attn_kernel(const short* __restrict__ Qb,
                                                   const short* __restrict__ Kb,
                                                   const short* __restrict__ Vt,
                                                   float* __restrict__ Op,
                                                   float* __restrict__ Ml) {
  __shared__ __align__(16) short Ksm[2][64 * 64];
  __shared__ __align__(16) short Vsm[2][64 * 64];
  __shared__ __align__(16) short Psm[4][16 * 64];
  int id = blockIdx.x;
  int qt = id & 31, hk = (id >> 5) & 3, b = (id >> 7) & 1, sp = id >> 8;
  int t = threadIdx.x, w = t >> 6, lane = t & 63;
  int l15 = lane & 15, g4 = lane >> 4;
  int h = hk * NG + w;

  const short* qbase = Qb + (((size_t)(b * NH + h)) * SQ + qt * 16) * 64;
  v8s aq[2];
#pragma unroll
  for (int s = 0; s < 2; ++s)
    aq[s] = *(const v8s*)(qbase + (size_t)l15 * 64 + s * 32 + g4 * 8);

  const short* kbase = Kb + ((size_t)(b * NHK + hk)) * SKV * 64;
  const short* vbase = Vt + ((size_t)(b * NHK + hk)) * 64 * SKV;
  char* pbase = (char*)&Psm[w][0];

  v4f acco[4] = {};
  float mrow[4], lrow[4];
#pragma unroll
  for (int r = 0; r < 4; ++r) { mrow[r] = -__builtin_inff(); lrow[r] = 0.f; }

  const int KV0 = sp * (SKV / NSPLIT);
  for (int kt = 0; kt < SKV / NSPLIT / 128; ++kt) {
    int kv0 = KV0 + kt * 128;
    __syncthreads();
    stage_tile<0, 2>(kbase, 64, kv0, 0, Ksm[0], t);
    stage_tile<0, 2>(kbase, 64, kv0 + 64, 0, Ksm[1], t);
    stage_tile<0, 2>(vbase, SKV, 0, kv0, Vsm[0], t);
    stage_tile<0, 2>(vbase, SKV, 0, kv0 + 64, Vsm[1], t);
    __syncthreads();

    v4f accs[8] = {};
#pragma unroll
    for (int hf = 0; hf < 2; ++hf)
#pragma unroll
      for (int f = 0; f < 4; ++f)
#pragma unroll
        for (int s = 0; s < 2; ++s) {
          v8s bk = lds_frag(Ksm[hf], f * 16 + l15, s * 64 + g4 * 16);
          accs[hf * 4 + f] =
              __builtin_amdgcn_mfma_f32_16x16x32_bf16(aq[s], bk, accs[hf * 4 + f], 0, 0, 0);
        }

    float tm[4];
#pragma unroll
    for (int r = 0; r < 4; ++r) {
      float m01 = fmaxf(accs[0][r], accs[1][r]), m23 = fmaxf(accs[2][r], accs[3][r]);
      float m45 = fmaxf(accs[4][r], accs[5][r]), m67 = fmaxf(accs[6][r], accs[7][r]);
      tm[r] = fmaxf(fmaxf(m01, m23), fmaxf(m45, m67));
    }
#pragma unroll
    for (int msk = 1; msk < 16; msk <<= 1)
#pragma unroll
      for (int r = 0; r < 4; ++r)
        tm[r] = fmaxf(tm[r], __shfl_xor(tm[r], msk));
    float al[4];
#pragma unroll
    for (int r = 0; r < 4; ++r) {
      float mn = fmaxf(mrow[r], tm[r]);
      al[r] = __expf(mrow[r] - mn);
      mrow[r] = mn;
    }
    float rs[4] = {0.f, 0.f, 0.f, 0.f};
#pragma unroll
    for (int f = 0; f < 8; ++f)
#pragma unroll
      for (int r = 0; r < 4; ++r) {
        accs[f][r] = __expf(accs[f][r] - mrow[r]);
        rs[r] += accs[f][r];
      }
#pragma unroll
    for (int msk = 1; msk < 16; msk <<= 1)
#pragma unroll
      for (int r = 0; r < 4; ++r) rs[r] += __shfl_xor(rs[r], msk);
#pragma unroll
    for (int r = 0; r < 4; ++r) lrow[r] = lrow[r] * al[r] + rs[r];
#pragma unroll
    for (int fd = 0; fd < 4; ++fd)
#pragma unroll
      for (int r = 0; r < 4; ++r) acco[fd][r] *= al[r];

#pragma unroll
    for (int hf = 0; hf < 2; ++hf) {
#pragma unroll
      for (int f = 0; f < 4; ++f)
#pragma unroll
        for (int r = 0; r < 4; ++r) {
          int row = g4 * 4 + r;
          int colB = (f * 16 + l15) * 2;
          *(short*)(pbase + row * 128 + (colB ^ ((row & 7) << 4))) = f2bf(accs[hf * 4 + f][r]);
        }
      asm volatile("s_waitcnt lgkmcnt(0)" ::: "memory");
      __builtin_amdgcn_sched_barrier(0);
      v8s pa[2];
#pragma unroll
      for (int s = 0; s < 2; ++s)
        pa[s] = *(const v8s*)(pbase + l15 * 128 + ((s * 64 + g4 * 16) ^ ((l15 & 7) << 4)));
      asm volatile("s_waitcnt lgkmcnt(0)" ::: "memory");
      __builtin_amdgcn_sched_barrier(0);
#pragma unroll
      for (int fd = 0; fd < 4; ++fd)
#pragma unroll
        for (int s = 0; s < 2; ++s) {
          v8s vb = lds_frag(Vsm[hf], fd * 16 + l15, s * 64 + g4 * 16);
          acco[fd] = __builtin_amdgcn_mfma_f32_16x16x32_bf16(pa[s], vb, acco[fd], 0, 0, 0);
        }
    }
  }

  size_t rowbase = ((size_t)b * NH + h) * SQ + qt * 16;
#pragma unroll
  for (int fd = 0; fd < 4; ++fd)
#pragma unroll
    for (int r = 0; r < 4; ++r) {
      int row = g4 * 4 + r;
      Op[((size_t)sp * RB + rowbase + row) * 64 + fd * 16 + l15] = acco[fd][r];
    }
  if (l15 == 0) {
#pragma unroll
    for (int r = 0; r < 4; ++r) {
      int row = g4 * 4 + r;
      v2f ml; ml[0] = mrow[r]; ml[1] = lrow[r];
      *(v2f*)(Ml + ((size_t)sp * RB + rowbase + row) * 2) = ml;
    }
  }
}

// Merge NSPLIT partials -> Ab bf16 [B, SQ, H*64]
__global__ __launch_bounds__(256) void merge_attn(const float* __restrict__ Op,
                                                  const float* __restrict__ Ml,
                                                  short* __restrict__ Ab) {
  int idx = blockIdx.x * 256 + threadIdx.x;  // RB*64 total
  int d = idx & 63, row = idx >> 6;
  float ms[NSPLIT], ls[NSPLIT];
  float M = -__builtin_inff();
#pragma unroll
  for (int s = 0; s < NSPLIT; ++s) {
    v2f ml = *(const v2f*)(Ml + ((size_t)s * RB + row) * 2);
    ms[s] = ml[0]; ls[s] = ml[1];
    M = fmaxf(M, ms[s]);
  }
  float L = 0.f, o = 0.f;
#pragma unroll
  for (int s = 0; s < NSPLIT; ++s) {
    float wgt = __expf(ms[s] - M);
    L += ls[s] * wgt;
    o += wgt * Op[((size_t)s * RB + row) * 64 + d];
  }
  int b = row >> 13;
  int hh = (row >> 9) & 15;
  int sq = row & 511;
  Ab[((size_t)(b * SQ + sq)) * HID + hh * 64 + d] = f2bf(o / L);
}

extern "C" void kernel_launch(void* const* d_in, const int* in_sizes, int n_in,
                              void* d_out, int out_size, void* d_ws, size_t ws_size,
                              hipStream_t stream) {
  const float* inputs = (const float*)d_in[0];  // [B,SKV,1024]
  const float* latent = (const float*)d_in[1];  // [B,SQ,1024]
  const float* wq = (const float*)d_in[2];      // [1024,1024]
  const float* wk = (const float*)d_in[3];      // [256,1024]
  const float* wv = (const float*)d_in[4];      // [256,1024]
  const float* wo = (const float*)d_in[5];      // [1024,1024]
  const float* qnw = (const float*)d_in[6];     // [64]
  const float* knw = (const float*)d_in[7];     // [64]

  char* ws = (char*)d_ws;
  float* Op  = (float*)(ws);                    // 16 MB  [NSPLIT, RB, 64] (dead after merge)
  float* Wop = (float*)(ws);                    // 16 MB  [4,1024,1024] wo partials (reuses Op)
  float* Ml  = (float*)(ws + 16777216);         // 0.5 MB [NSPLIT, RB, 2]
  short* Qb  = (short*)(ws + 17825792);         // 2 MB   [B,NH,SQ,64]
  short* Kb  = (short*)(ws + 19922944);         // 4 MB   [B,NHK,SKV,64]
  short* Vtb = (short*)(ws + 24117248);         // 4 MB   [B,NHK,64,SKV]
  short* Ab  = (short*)(ws + 28311552);         // 2 MB   [B,SQ,1024]

  proj_all<<<640, 256, 0, stream>>>(inputs, latent, wq, wk, wv, qnw, knw, Qb, Kb, Vtb);
  attn_kernel<<<256 * NSPLIT, 256, 0, stream>>>(Qb, Kb, Vtb, Op, Ml);
  merge_attn<<<RB * 64 / 256, 256, 0, stream>>>(Op, Ml, Ab);
  wo_gemm<<<512, 256, 0, stream>>>(Ab, wo, Wop);
  wo_reduce<<<1024, 256, 0, stream>>>(Wop, (float*)d_out);
}

// Round 12
// 199.831 us; speedup vs baseline: 1.8543x; 1.0706x over previous
//
#include <hip/hip_runtime.h>

#define NB 2
#define SQ 512
#define SKV 4096
#define HID 1024
#define NH 16
#define NHK 4
#define NG 4
#define HD 64
#define EPSF 1e-6f
#define NSPLIT 4
#define RB (NB * NH * SQ)  // 16384 total q-rows

typedef short v8s __attribute__((ext_vector_type(8)));
typedef short v4s __attribute__((ext_vector_type(4)));
typedef float v4f __attribute__((ext_vector_type(4)));
typedef float v2f __attribute__((ext_vector_type(2)));

// branchless RTNE f32->bf16 bit-trick. NOT the (__bf16) HW cast: that emits a
// NaN-correct v_cmp/v_cndmask pair per element which serializes on VCC —
// measured +21us on attn_kernel (r8->r9 A/B, 61->82.5us).
static __device__ __forceinline__ short f2bf(float f) {
  unsigned u = __builtin_bit_cast(unsigned, f);
  u += 0x7FFFu + ((u >> 16) & 1u);
  return (short)(u >> 16);
}

// swizzled LDS fragment read: row-major [R][64] bf16 tile, 128B rows,
// byte ^= (row&7)<<4  (conflict-free for 16-row x 4-group b128 reads)
static __device__ __forceinline__ v8s lds_frag(const short* lds, int row, int kbyte) {
  return *(const v8s*)((const char*)lds + row * 128 + (kbyte ^ ((row & 7) << 4)));
}

// ---- 2-phase pipeline staging helpers (r11->r12): loads land in f32 regs with NO
// dependent ops until stage_write after the MFMA block -> HBM latency hides under
// compute; f2bf happens at write time behind the natural vmcnt wait. ----
template<int NIT>
static __device__ __forceinline__ void stage_load_f32(const float* src, int ld,
                                                      int r0, int c0, int t, v4f* regs) {
#pragma unroll
  for (int i = 0; i < NIT; ++i) {
    int flat = t * 8 + i * 2048;
    int row = flat >> 6, col = flat & 63;
    const float* p = src + (size_t)(r0 + row) * ld + c0 + col;
    regs[2 * i] = *(const v4f*)p;
    regs[2 * i + 1] = *(const v4f*)(p + 4);
  }
}

template<int NIT>
static __device__ __forceinline__ void stage_write_bf16(const v4f* regs, short* lds, int t) {
#pragma unroll
  for (int i = 0; i < NIT; ++i) {
    int flat = t * 8 + i * 2048;
    int row = flat >> 6, col = flat & 63;
    v4f a = regs[2 * i], b = regs[2 * i + 1];
    v8s v;
    v[0] = f2bf(a[0]); v[1] = f2bf(a[1]); v[2] = f2bf(a[2]); v[3] = f2bf(a[3]);
    v[4] = f2bf(b[0]); v[5] = f2bf(b[1]); v[6] = f2bf(b[2]); v[7] = f2bf(b[3]);
    *(v8s*)((char*)lds + row * 128 + ((col * 2) ^ ((row & 7) << 4))) = v;
  }
}

template<int NIT>
static __device__ __forceinline__ void stage_load_bf16(const short* src, int ld,
                                                       int r0, int c0, int t, v8s* regs) {
#pragma unroll
  for (int i = 0; i < NIT; ++i) {
    int flat = t * 8 + i * 2048;
    int row = flat >> 6, col = flat & 63;
    regs[i] = *(const v8s*)(src + (size_t)(r0 + row) * ld + c0 + col);
  }
}

template<int NIT>
static __device__ __forceinline__ void stage_write_raw(const v8s* regs, short* lds, int t) {
#pragma unroll
  for (int i = 0; i < NIT; ++i) {
    int flat = t * 8 + i * 2048;
    int row = flat >> 6, col = flat & 63;
    *(v8s*)((char*)lds + row * 128 + ((col * 2) ^ ((row & 7) << 4))) = regs[i];
  }
}

// non-pipelined stage (attn still uses this; bf16 path only)
template<int NIT>
static __device__ __forceinline__ void stage_tile_b(const short* src, int ld,
                                                    int r0, int c0, short* lds, int t) {
#pragma unroll
  for (int i = 0; i < NIT; ++i) {
    int flat = t * 8 + i * 2048;
    int row = flat >> 6, col = flat & 63;
    v8s v = *(const v8s*)(src + (size_t)(r0 + row) * ld + c0 + col);
    *(v8s*)((char*)lds + row * 128 + ((col * 2) ^ ((row & 7) << 4))) = v;
  }
}

#define KV_ASZ (128 * 64)  // A region rows*64 (K/V branch)
#define Q_ASZ (64 * 64)    // A region (Q branch / wo)

// Unified Q/K/V projection, 640 blocks, XCD-aware mapping (r11) + single-barrier
// double-buffered pipeline (r12). smem blob [2][192*64] = 48KB -> 3 blocks/CU cap.
//  K/V [0,512): xcd=bid&7 owns mblk in [xcd*8,xcd*8+8); slot=bid>>3: mblk=xcd*8+(slot>>3),
//    zh=slot&7 (z=zh&1, head=zh>>1). BM=128,BN=64.
//  Q [512,640): r=bid-512, xcd=r&7; nblk=(slot&1)|((xcd&3)<<1), mblk=((slot>>1)&7)|((xcd>>2)<<3).
//    BM=64, BN=128 (2 heads).
__global__ __launch_bounds__(256) void proj_all(const float* __restrict__ inputs,
                                                const float* __restrict__ latent,
                                                const float* __restrict__ wq,
                                                const float* __restrict__ wk,
                                                const float* __restrict__ wv,
                                                const float* __restrict__ qnw,
                                                const float* __restrict__ knw,
                                                short* __restrict__ Qb,
                                                short* __restrict__ Kb,
                                                short* __restrict__ Vtb) {
  __shared__ __align__(16) short smem[2][192 * 64];
  const int bid = blockIdx.x;
  const int t = threadIdx.x, lane = t & 63, w = t >> 6;
  const int l15 = lane & 15, g4 = lane >> 4;
  v4f acc[2][4] = {};

  if (bid < 512) {  // ---- K/V branch ----
    const int xcd = bid & 7, slot = bid >> 3;
    const int mblk = xcd * 8 + (slot >> 3);
    const int zh = slot & 7;
    const int z = zh & 1, head = zh >> 1;
    const int m0 = mblk * 128;
    const float* W = z ? wv : wk;
    v4f ar[8], br[4];
    stage_load_f32<4>(inputs, HID, m0, 0, t, ar);
    stage_load_f32<2>(W, HID, head * 64, 0, t, br);
    stage_write_bf16<4>(ar, &smem[0][0], t);
    stage_write_bf16<2>(br, &smem[0][KV_ASZ], t);
    for (int kt = 0; kt < 16; ++kt) {
      __syncthreads();
      const short* Acur = &smem[kt & 1][0];
      const short* Bcur = &smem[kt & 1][KV_ASZ];
      int kn = ((kt + 1) & 15) * 64;  // last iter re-loads tile 0 (uniform, discarded)
      stage_load_f32<4>(inputs, HID, m0, kn, t, ar);
      stage_load_f32<2>(W, HID, head * 64, kn, t, br);
      v8s af[2][2], bfr[4][2];
#pragma unroll
      for (int mf = 0; mf < 2; ++mf)
#pragma unroll
        for (int s = 0; s < 2; ++s)
          af[mf][s] = lds_frag(Acur, w * 32 + mf * 16 + l15, s * 64 + g4 * 16);
#pragma unroll
      for (int nf = 0; nf < 4; ++nf)
#pragma unroll
        for (int s = 0; s < 2; ++s)
          bfr[nf][s] = lds_frag(Bcur, nf * 16 + l15, s * 64 + g4 * 16);
#pragma unroll
      for (int mf = 0; mf < 2; ++mf)
#pragma unroll
        for (int nf = 0; nf < 4; ++nf)
#pragma unroll
          for (int s = 0; s < 2; ++s)
            acc[mf][nf] = __builtin_amdgcn_mfma_f32_16x16x32_bf16(af[mf][s], bfr[nf][s],
                                                                  acc[mf][nf], 0, 0, 0);
      if (kt + 1 < 16) {
        short* An = &smem[(kt + 1) & 1][0];
        stage_write_bf16<4>(ar, An, t);
        stage_write_bf16<2>(br, An + KV_ASZ, t);
      }
    }
    if (!z) {  // K: rmsnorm -> Kb [B,NHK,SKV,64]
      float wcol[4];
#pragma unroll
      for (int nf = 0; nf < 4; ++nf) wcol[nf] = knw[nf * 16 + l15];
#pragma unroll
      for (int mf = 0; mf < 2; ++mf)
#pragma unroll
        for (int j = 0; j < 4; ++j) {
          float ss = acc[mf][0][j] * acc[mf][0][j] + acc[mf][1][j] * acc[mf][1][j] +
                     acc[mf][2][j] * acc[mf][2][j] + acc[mf][3][j] * acc[mf][3][j];
#pragma unroll
          for (int msk = 1; msk < 16; msk <<= 1) ss += __shfl_xor(ss, msk);
          float sc = rsqrtf(ss * (1.0f / 64.0f) + EPSF);
          int m = m0 + w * 32 + mf * 16 + g4 * 4 + j;
          int b = m >> 12, sl = m & (SKV - 1);
          size_t base = ((size_t)(b * NHK + head) * SKV + sl) * 64;
#pragma unroll
          for (int nf = 0; nf < 4; ++nf)
            Kb[base + nf * 16 + l15] = f2bf(acc[mf][nf][j] * sc * wcol[nf]);
        }
    } else {  // V: transposed -> Vtb [B,NHK,64,SKV]
#pragma unroll
      for (int mf = 0; mf < 2; ++mf) {
        int m = m0 + w * 32 + mf * 16 + g4 * 4;
        int b = m >> 12, sl = m & (SKV - 1);
#pragma unroll
        for (int nf = 0; nf < 4; ++nf) {
          int d = nf * 16 + l15;
          v4s o;
#pragma unroll
          for (int j = 0; j < 4; ++j) o[j] = f2bf(acc[mf][nf][j]);
          *(v4s*)(Vtb + ((size_t)(b * NHK + head) * 64 + d) * SKV + sl) = o;
        }
      }
    }
  } else {  // ---- Q branch ----
    const int r = bid - 512;
    const int xcd = r & 7, slot = r >> 3;
    const int nblk = (slot & 1) | ((xcd & 3) << 1);
    const int mblk = ((slot >> 1) & 7) | ((xcd >> 2) << 3);
    const int m0 = mblk * 64;
    const int wr = w >> 1, wc = w & 1;
    v4f ar[4], br[8];
    stage_load_f32<2>(latent, HID, m0, 0, t, ar);
    stage_load_f32<4>(wq, HID, nblk * 128, 0, t, br);
    stage_write_bf16<2>(ar, &smem[0][0], t);
    stage_write_bf16<4>(br, &smem[0][Q_ASZ], t);
    for (int kt = 0; kt < 16; ++kt) {
      __syncthreads();
      const short* Acur = &smem[kt & 1][0];
      const short* Bcur = &smem[kt & 1][Q_ASZ];
      int kn = ((kt + 1) & 15) * 64;
      stage_load_f32<2>(latent, HID, m0, kn, t, ar);
      stage_load_f32<4>(wq, HID, nblk * 128, kn, t, br);
      v8s af[2][2], bfr[4][2];
#pragma unroll
      for (int mf = 0; mf < 2; ++mf)
#pragma unroll
        for (int s = 0; s < 2; ++s)
          af[mf][s] = lds_frag(Acur, wr * 32 + mf * 16 + l15, s * 64 + g4 * 16);
#pragma unroll
      for (int nf = 0; nf < 4; ++nf)
#pragma unroll
        for (int s = 0; s < 2; ++s)
          bfr[nf][s] = lds_frag(Bcur, wc * 64 + nf * 16 + l15, s * 64 + g4 * 16);
#pragma unroll
      for (int mf = 0; mf < 2; ++mf)
#pragma unroll
        for (int nf = 0; nf < 4; ++nf)
#pragma unroll
          for (int s = 0; s < 2; ++s)
            acc[mf][nf] = __builtin_amdgcn_mfma_f32_16x16x32_bf16(af[mf][s], bfr[nf][s],
                                                                  acc[mf][nf], 0, 0, 0);
      if (kt + 1 < 16) {
        short* An = &smem[(kt + 1) & 1][0];
        stage_write_bf16<2>(ar, An, t);
        stage_write_bf16<4>(br, An + Q_ASZ, t);
      }
    }
    const int head = nblk * 2 + wc;
    float wcol[4];
#pragma unroll
    for (int nf = 0; nf < 4; ++nf) wcol[nf] = qnw[nf * 16 + l15];
#pragma unroll
    for (int mf = 0; mf < 2; ++mf)
#pragma unroll
      for (int j = 0; j < 4; ++j) {
        float ss = acc[mf][0][j] * acc[mf][0][j] + acc[mf][1][j] * acc[mf][1][j] +
                   acc[mf][2][j] * acc[mf][2][j] + acc[mf][3][j] * acc[mf][3][j];
#pragma unroll
        for (int msk = 1; msk < 16; msk <<= 1) ss += __shfl_xor(ss, msk);
        float sc = rsqrtf(ss * (1.0f / 64.0f) + EPSF);
        int m = m0 + wr * 32 + mf * 16 + g4 * 4 + j;
        int b = m >> 9, sl = m & (SQ - 1);
        size_t base = ((size_t)(b * NH + head) * SQ + sl) * 64;
#pragma unroll
        for (int nf = 0; nf < 4; ++nf)
          Qb[base + nf * 16 + l15] = f2bf(acc[mf][nf][j] * sc * wcol[nf]);
      }
  }
}

// WO gemm, K-split x4, XCD-aware (xcd=bid&7=nblk), 2-phase pipelined like proj_all.
// 512 blocks; slot=bid>>3: mblk=slot&15, ks=slot>>4. BM=64, BN=128, wave owns 32x64.
__global__ __launch_bounds__(256) void wo_gemm(const short* __restrict__ Ab,
                                               const float* __restrict__ Wo,
                                               float* __restrict__ Wop) {
  __shared__ __align__(16) short smem[2][192 * 64];
  const int t = threadIdx.x, lane = t & 63, w = t >> 6;
  const int l15 = lane & 15, g4 = lane >> 4;
  const int wr = w >> 1, wc = w & 1;
  const int p = blockIdx.x;
  const int nblk = p & 7, slot = p >> 3;
  const int m0 = (slot & 15) * 64, n0 = nblk * 128, ks = slot >> 4;
  v4f acc[2][4] = {};
  v8s ar[2];
  v4f br[8];
  stage_load_bf16<2>(Ab, HID, m0, ks * 256, t, ar);
  stage_load_f32<4>(Wo, HID, n0, ks * 256, t, br);
  stage_write_raw<2>(ar, &smem[0][0], t);
  stage_write_bf16<4>(br, &smem[0][Q_ASZ], t);
  for (int kk = 0; kk < 4; ++kk) {
    __syncthreads();
    const short* Acur = &smem[kk & 1][0];
    const short* Bcur = &smem[kk & 1][Q_ASZ];
    int kn = ks * 256 + ((kk + 1) & 3) * 64;
    stage_load_bf16<2>(Ab, HID, m0, kn, t, ar);
    stage_load_f32<4>(Wo, HID, n0, kn, t, br);
    v8s af[2][2], bfr[4][2];
#pragma unroll
    for (int mf = 0; mf < 2; ++mf)
#pragma unroll
      for (int s = 0; s < 2; ++s)
        af[mf][s] = lds_frag(Acur, wr * 32 + mf * 16 + l15, s * 64 + g4 * 16);
#pragma unroll
    for (int nf = 0; nf < 4; ++nf)
#pragma unroll
      for (int s = 0; s < 2; ++s)
        bfr[nf][s] = lds_frag(Bcur, wc * 64 + nf * 16 + l15, s * 64 + g4 * 16);
#pragma unroll
    for (int mf = 0; mf < 2; ++mf)
#pragma unroll
      for (int nf = 0; nf < 4; ++nf)
#pragma unroll
        for (int s = 0; s < 2; ++s)
          acc[mf][nf] = __builtin_amdgcn_mfma_f32_16x16x32_bf16(af[mf][s], bfr[nf][s],
                                                                acc[mf][nf], 0, 0, 0);
    if (kk + 1 < 4) {
      short* An = &smem[(kk + 1) & 1][0];
      stage_write_raw<2>(ar, An, t);
      stage_write_bf16<4>(br, An + Q_ASZ, t);
    }
  }
  float* C = Wop + (size_t)ks * HID * NB * SQ;
#pragma unroll
  for (int mf = 0; mf < 2; ++mf)
#pragma unroll
    for (int j = 0; j < 4; ++j) {
      int m = m0 + wr * 32 + mf * 16 + g4 * 4 + j;
#pragma unroll
      for (int nf = 0; nf < 4; ++nf)
        C[(size_t)m * HID + n0 + wc * 64 + nf * 16 + l15] = acc[mf][nf][j];
    }
}

// Sum 4 K-split partials -> d_out f32
__global__ __launch_bounds__(256) void wo_reduce(const float* __restrict__ Wop,
                                                 float* __restrict__ out) {
  int idx = (blockIdx.x * 256 + threadIdx.x) * 4;
  v4f s = *(const v4f*)(Wop + idx);
#pragma unroll
  for (int ks = 1; ks < 4; ++ks) {
    v4f p = *(const v4f*)(Wop + (size_t)ks * HID * NB * SQ + idx);
    s[0] += p[0]; s[1] += p[1]; s[2] += p[2]; s[3] += p[3];
  }
  *(v4f*)(out + idx) = s;
}

// Flash attention, KV-split, KVBLK=128 (two 64-tiles per barrier pair, batched softmax).
// block = (split, b, hk, qt16); 4 waves = 4 GQA heads sharing K/V tiles.  (UNCHANGED)
__global__ __launch_bounds__(256) void attn_kernel(const short* __restrict__ Qb,
                                                   const short* __restrict__ Kb,
                                                   const short* __restrict__ Vt,
                                                   float* __restrict__ Op,
                                                   float* __restrict__ Ml) {
  __shared__ __align__(16) short Ksm[2][64 * 64];
  __shared__ __align__(16) short Vsm[2][64 * 64];
  __shared__ __align__(16) short Psm[4][16 * 64];
  int id = blockIdx.x;
  int qt = id & 31, hk = (id >> 5) & 3, b = (id >> 7) & 1, sp = id >> 8;
  int t = threadIdx.x, w = t >> 6, lane = t & 63;
  int l15 = lane & 15, g4 = lane >> 4;
  int h = hk * NG + w;

  const short* qbase = Qb + (((size_t)(b * NH + h)) * SQ + qt * 16) * 64;
  v8s aq[2];
#pragma unroll
  for (int s = 0; s < 2; ++s)
    aq[s] = *(const v8s*)(qbase + (size_t)l15 * 64 + s * 32 + g4 * 8);

  const short* kbase = Kb + ((size_t)(b * NHK + hk)) * SKV * 64;
  const short* vbase = Vt + ((size_t)(b * NHK + hk)) * 64 * SKV;
  char* pbase = (char*)&Psm[w][0];

  v4f acco[4] = {};
  float mrow[4], lrow[4];
#pragma unroll
  for (int r = 0; r < 4; ++r) { mrow[r] = -__builtin_inff(); lrow[r] = 0.f; }

  const int KV0 = sp * (SKV / NSPLIT);
  for (int kt = 0; kt < SKV / NSPLIT / 128; ++kt) {
    int kv0 = KV0 + kt * 128;
    __syncthreads();
    stage_tile_b<2>(kbase, 64, kv0, 0, Ksm[0], t);
    stage_tile_b<2>(kbase, 64, kv0 + 64, 0, Ksm[1], t);
    stage_tile_b<2>(vbase, SKV, 0, kv0, Vsm[0], t);
    stage_tile_b<2>(vbase, SKV, 0, kv0 + 64, Vsm[1], t);
    __syncthreads();

    v4f accs[8] = {};
#pragma unroll
    for (int hf = 0; hf < 2; ++hf)
#pragma unroll
      for (int f = 0; f < 4; ++f)
#pragma unroll
        for (int s = 0; s < 2; ++s) {
          v8s bk = lds_frag(Ksm[hf], f * 16 + l15, s * 64 + g4 * 16);
          accs[hf * 4 + f] =
              __builtin_amdgcn_mfma_f32_16x16x32_bf16(aq[s], bk, accs[hf * 4 + f], 0, 0, 0);
        }

    float tm[4];
#pragma unroll
    for (int r = 0; r < 4; ++r) {
      float m01 = fmaxf(accs[0][r], accs[1][r]), m23 = fmaxf(accs[2][r], accs[3][r]);
      float m45 = fmaxf(accs[4][r], accs[5][r]), m67 = fmaxf(accs[6][r], accs[7][r]);
      tm[r] = fmaxf(fmaxf(m01, m23), fmaxf(m45, m67));
    }
#pragma unroll
    for (int msk = 1; msk < 16; msk <<= 1)
#pragma unroll
      for (int r = 0; r < 4; ++r)
        tm[r] = fmaxf(tm[r], __shfl_xor(tm[r], msk));
    float al[4];
#pragma unroll
    for (int r = 0; r < 4; ++r) {
      float mn = fmaxf(mrow[r], tm[r]);
      al[r] = __expf(mrow[r] - mn);
      mrow[r] = mn;
    }
    float rs[4] = {0.f, 0.f, 0.f, 0.f};
#pragma unroll
    for (int f = 0; f < 8; ++f)
#pragma unroll
      for (int r = 0; r < 4; ++r) {
        accs[f][r] = __expf(accs[f][r] - mrow[r]);
        rs[r] += accs[f][r];
      }
#pragma unroll
    for (int msk = 1; msk < 16; msk <<= 1)
#pragma unroll
      for (int r = 0; r < 4; ++r) rs[r] += __shfl_xor(rs[r], msk);
#pragma unroll
    for (int r = 0; r < 4; ++r) lrow[r] = lrow[r] * al[r] + rs[r];
#pragma unroll
    for (int fd = 0; fd < 4; ++fd)
#pragma unroll
      for (int r = 0; r < 4; ++r) acco[fd][r] *= al[r];

#pragma unroll
    for (int hf = 0; hf < 2; ++hf) {
#pragma unroll
      for (int f = 0; f < 4; ++f)
#pragma unroll
        for (int r = 0; r < 4; ++r) {
          int row = g4 * 4 + r;
          int colB = (f * 16 + l15) * 2;
          *(short*)(pbase + row * 128 + (colB ^ ((row & 7) << 4))) = f2bf(accs[hf * 4 + f][r]);
        }
      asm volatile("s_waitcnt lgkmcnt(0)" ::: "memory");
      __builtin_amdgcn_sched_barrier(0);
      v8s pa[2];
#pragma unroll
      for (int s = 0; s < 2; ++s)
        pa[s] = *(const v8s*)(pbase + l15 * 128 + ((s * 64 + g4 * 16) ^ ((l15 & 7) << 4)));
      asm volatile("s_waitcnt lgkmcnt(0)" ::: "memory");
      __builtin_amdgcn_sched_barrier(0);
#pragma unroll
      for (int fd = 0; fd < 4; ++fd)
#pragma unroll
        for (int s = 0; s < 2; ++s) {
          v8s vb = lds_frag(Vsm[hf], fd * 16 + l15, s * 64 + g4 * 16);
          acco[fd] = __builtin_amdgcn_mfma_f32_16x16x32_bf16(pa[s], vb, acco[fd], 0, 0, 0);
        }
    }
  }

  size_t rowbase = ((size_t)b * NH + h) * SQ + qt * 16;
#pragma unroll
  for (int fd = 0; fd < 4; ++fd)
#pragma unroll
    for (int r = 0; r < 4; ++r) {
      int row = g4 * 4 + r;
      Op[((size_t)sp * RB + rowbase + row) * 64 + fd * 16 + l15] = acco[fd][r];
    }
  if (l15 == 0) {
#pragma unroll
    for (int r = 0; r < 4; ++r) {
      int row = g4 * 4 + r;
      v2f ml; ml[0] = mrow[r]; ml[1] = lrow[r];
      *(v2f*)(Ml + ((size_t)sp * RB + rowbase + row) * 2) = ml;
    }
  }
}

// Merge NSPLIT partials -> Ab bf16 [B, SQ, H*64]
__global__ __launch_bounds__(256) void merge_attn(const float* __restrict__ Op,
                                                  const float* __restrict__ Ml,
                                                  short* __restrict__ Ab) {
  int idx = blockIdx.x * 256 + threadIdx.x;  // RB*64 total
  int d = idx & 63, row = idx >> 6;
  float ms[NSPLIT], ls[NSPLIT];
  float M = -__builtin_inff();
#pragma unroll
  for (int s = 0; s < NSPLIT; ++s) {
    v2f ml = *(const v2f*)(Ml + ((size_t)s * RB + row) * 2);
    ms[s] = ml[0]; ls[s] = ml[1];
    M = fmaxf(M, ms[s]);
  }
  float L = 0.f, o = 0.f;
#pragma unroll
  for (int s = 0; s < NSPLIT; ++s) {
    float wgt = __expf(ms[s] - M);
    L += ls[s] * wgt;
    o += wgt * Op[((size_t)s * RB + row) * 64 + d];
  }
  int b = row >> 13;
  int hh = (row >> 9) & 15;
  int sq = row & 511;
  Ab[((size_t)(b * SQ + sq)) * HID + hh * 64 + d] = f2bf(o / L);
}

extern "C" void kernel_launch(void* const* d_in, const int* in_sizes, int n_in,
                              void* d_out, int out_size, void* d_ws, size_t ws_size,
                              hipStream_t stream) {
  const float* inputs = (const float*)d_in[0];  // [B,SKV,1024]
  const float* latent = (const float*)d_in[1];  // [B,SQ,1024]
  const float* wq = (const float*)d_in[2];      // [1024,1024]
  const float* wk = (const float*)d_in[3];      // [256,1024]
  const float* wv = (const float*)d_in[4];      // [256,1024]
  const float* wo = (const float*)d_in[5];      // [1024,1024]
  const float* qnw = (const float*)d_in[6];     // [64]
  const float* knw = (const float*)d_in[7];     // [64]

  char* ws = (char*)d_ws;
  float* Op  = (float*)(ws);                    // 16 MB  [NSPLIT, RB, 64] (dead after merge)
  float* Wop = (float*)(ws);                    // 16 MB  [4,1024,1024] wo partials (reuses Op)
  float* Ml  = (float*)(ws + 16777216);         // 0.5 MB [NSPLIT, RB, 2]
  short* Qb  = (short*)(ws + 17825792);         // 2 MB   [B,NH,SQ,64]
  short* Kb  = (short*)(ws + 19922944);         // 4 MB   [B,NHK,SKV,64]
  short* Vtb = (short*)(ws + 24117248);         // 4 MB   [B,NHK,64,SKV]
  short* Ab  = (short*)(ws + 28311552);         // 2 MB   [B,SQ,1024]

  proj_all<<<640, 256, 0, stream>>>(inputs, latent, wq, wk, wv, qnw, knw, Qb, Kb, Vtb);
  attn_kernel<<<256 * NSPLIT, 256, 0, stream>>>(Qb, Kb, Vtb, Op, Ml);
  merge_attn<<<RB * 64 / 256, 256, 0, stream>>>(Op, Ml, Ab);
  wo_gemm<<<512, 256, 0, stream>>>(Ab, wo, Wop);
  wo_reduce<<<1024, 256, 0, stream>>>(Wop, (float*)d_out);
}